// Round 9
// baseline (1167.278 us; speedup 1.0000x reference)
//
#include <hip/hip_runtime.h>

// AGLI_5703716569604 — round 8: fused att_gemm (att+attT+all 3 stat sets),
// drop colstats/rowstats/att2_stream; attmap computes att2 on the fly.
// B=2, ch1=64, ch2=128, H=W=64, N=4096, att [B,4096,4096].

#define LB __launch_bounds__(256)

constexpr float BN_SCALE = 0.99999500003749968f; // 1/sqrt(1+1e-5)
constexpr float NEG_BIG  = -3.402823466e38f;
constexpr float LOG2E    = 1.4426950408889634f;
constexpr float LN2      = 0.6931471805599453f;

typedef __attribute__((ext_vector_type(8))) short short8v;
typedef __attribute__((ext_vector_type(4))) float f32x4;

__device__ __forceinline__ ushort bf16rne(float f) {
    unsigned u = __float_as_uint(f);
    unsigned r = (u + 0x7FFFu + ((u >> 16) & 1u)) >> 16;
    return (ushort)r;
}

__device__ __forceinline__ void online_upd(float& mx, float& sm, float v) {
    if (v > mx) { sm = sm * __expf(mx - v) + 1.f; mx = v; }
    else        { sm += __expf(v - mx); }
}
__device__ __forceinline__ void online_merge(float& mx, float& sm, float m2, float s2) {
    const float mn = fmaxf(mx, m2);
    sm = sm * __expf(mx - mn) + s2 * __expf(m2 - mn);
    mx = mn;
}

// ---------------------------------------------------------------------------
// Stage one 34x34 halo tile (stride 35) for input channel image ib.
__device__ __forceinline__ void stage_tile(const float* __restrict__ ib,
                                           float* __restrict__ buf,
                                           int x0, int y0, int tid)
{
    #pragma unroll
    for (int r = 0; r < 5; ++r) {
        const int e = tid + r * 256;
        if (e < 1156) {
            const int hy = e / 34, hx = e % 34;
            const int yy = y0 + hy - 1, xx = x0 + hx - 1;
            float v = 0.f;
            if ((unsigned)yy < 64u && (unsigned)xx < 64u)
                v = ib[yy * 64 + xx];
            buf[hy * 35 + hx] = v;
        }
    }
}

// ---------------------------------------------------------------------------
// 3x3 conv partial over an ic-chunk (unchanged).
__global__ LB void conv3x3_big(
    const float* __restrict__ in, const float* __restrict__ gconst,
    const float* __restrict__ w, const float* __restrict__ bias,
    float* __restrict__ part, int Cg, int Cin, int Cout, int ICS)
{
    __shared__ float buf[2][34 * 35];
    __shared__ float wg[8][10];
    const int tid = threadIdx.x;
    const int tx = tid & 15, ty = tid >> 4;
    const int x0 = (blockIdx.x & 1) * 32, y0 = (blockIdx.x >> 1) * 32;
    const int oc0 = blockIdx.y * 8;
    const int b = blockIdx.z / ICS, s = blockIdx.z % ICS;
    const int chunk = Cin / ICS;
    const int ic0 = s * chunk;
    const int Ct = Cg + Cin;
    const int HW = 4096;

    float acc[8][4];
    #pragma unroll
    for (int oc = 0; oc < 8; ++oc)
        #pragma unroll
        for (int p = 0; p < 4; ++p) acc[oc][p] = 0.f;

    if (s == 0) {
        if (bias) {
            #pragma unroll
            for (int oc = 0; oc < 8; ++oc) {
                const float bv = bias[oc0 + oc];
                #pragma unroll
                for (int p = 0; p < 4; ++p) acc[oc][p] = bv;
            }
        }
        if (Cg > 0) {
            for (int e = tid; e < 72; e += 256) {
                const int oc = e / 9, k = e % 9;
                float sm = 0.f;
                for (int ic = 0; ic < Cg; ++ic)
                    sm += gconst[b * Cg + ic] * w[((long)(oc0 + oc) * Ct + ic) * 9 + k];
                wg[oc][k] = sm;
            }
            __syncthreads();
            #pragma unroll
            for (int k = 0; k < 9; ++k) {
                const int dy = k / 3 - 1, dx = k % 3 - 1;
                #pragma unroll
                for (int pr = 0; pr < 2; ++pr)
                    #pragma unroll
                    for (int pc = 0; pc < 2; ++pc) {
                        const int yy = y0 + ty * 2 + pr + dy;
                        const int xx = x0 + tx * 2 + pc + dx;
                        if ((unsigned)yy < 64u && (unsigned)xx < 64u) {
                            #pragma unroll
                            for (int oc = 0; oc < 8; ++oc)
                                acc[oc][pr * 2 + pc] += wg[oc][k];
                        }
                    }
            }
        }
    }

    const float* ib = in + ((long)b * Cin + ic0) * HW;
    stage_tile(ib, buf[0], x0, y0, tid);
    __syncthreads();
    int cur = 0;
    for (int i = 0; i < chunk; ++i) {
        if (i + 1 < chunk)
            stage_tile(ib + (long)(i + 1) * HW, buf[cur ^ 1], x0, y0, tid);
        float win[4][4];
        const float* bp = buf[cur] + (ty * 2) * 35 + tx * 2;
        #pragma unroll
        for (int r = 0; r < 4; ++r) {
            const float2 a = *(const float2*)&bp[r * 35];
            const float2 c = *(const float2*)&bp[r * 35 + 2];
            win[r][0] = a.x; win[r][1] = a.y; win[r][2] = c.x; win[r][3] = c.y;
        }
        const float* wq = w + ((long)oc0 * Ct + Cg + ic0 + i) * 9;
        #pragma unroll
        for (int oc = 0; oc < 8; ++oc) {
            const float* wo = wq + (long)oc * Ct * 9;
            #pragma unroll
            for (int dy = 0; dy < 3; ++dy)
                #pragma unroll
                for (int dx = 0; dx < 3; ++dx) {
                    const float wv = wo[dy * 3 + dx];
                    #pragma unroll
                    for (int pr = 0; pr < 2; ++pr)
                        #pragma unroll
                        for (int pc = 0; pc < 2; ++pc)
                            acc[oc][pr * 2 + pc] =
                                fmaf(wv, win[pr + dy][pc + dx], acc[oc][pr * 2 + pc]);
                }
        }
        __syncthreads();
        cur ^= 1;
    }

    #pragma unroll
    for (int oc = 0; oc < 8; ++oc) {
        #pragma unroll
        for (int pr = 0; pr < 2; ++pr) {
            float* q = part + (((long)s * 2 + b) * Cout + oc0 + oc) * (long)HW
                       + (y0 + ty * 2 + pr) * 64 + x0 + tx * 2;
            *(float2*)q = make_float2(acc[oc][pr * 2], acc[oc][pr * 2 + 1]);
        }
    }
}

// ---------------------------------------------------------------------------
__global__ LB void conv_combine(const float* __restrict__ part,
                                const float* __restrict__ bn,
                                const float* __restrict__ residual,
                                float* __restrict__ out,
                                int Cout, int ICS)
{
    const long idx = (long)blockIdx.x * 256 + threadIdx.x;
    const int hw = (int)(idx & 4095);
    const long t = idx >> 12;
    const int c = (int)(t % Cout);
    const int b = (int)(t / Cout);
    float v = 0.f;
    for (int s = 0; s < ICS; ++s)
        v += part[(((long)s * 2 + b) * Cout + c) * 4096 + hw];
    const float scale = bn[c] * BN_SCALE, beta = bn[Cout + c];
    float r = fmaxf(fmaf(v, scale, beta), 0.f);
    if (residual) r += residual[idx];
    out[idx] = r;
}

// ---------------------------------------------------------------------------
__global__ LB void gap_kernel(const float* __restrict__ in,
                              float* __restrict__ o1, float* __restrict__ o2,
                              int C, int HW)
{
    const int c = blockIdx.x, b = blockIdx.y;
    const float* p = in + ((long)b * C + c) * HW;
    float s = 0.f;
    for (int i = threadIdx.x; i < HW; i += 256) s += p[i];
    #pragma unroll
    for (int off = 32; off; off >>= 1) s += __shfl_down(s, off);
    __shared__ float red[4];
    if ((threadIdx.x & 63) == 0) red[threadIdx.x >> 6] = s;
    __syncthreads();
    if (threadIdx.x == 0) {
        const float t = (red[0] + red[1] + red[2] + red[3]) / (float)HW;
        o1[b * C + c] = t;
        o2[b * C + c] = t;
    }
}

// ---------------------------------------------------------------------------
// Cross-thread (over m) online-softmax reduce of 16 per-thread values.
// Result: per row r (0..15), stats over the block's 256 m values.
__device__ __forceinline__ void rowred(float (&ldsR)[16][272], const float (&vals)[16],
                                       float* __restrict__ Pm, float* __restrict__ Ps,
                                       int tid, long idx_base)
{
    #pragma unroll
    for (int nn = 0; nn < 16; ++nn) ldsR[nn][tid] = vals[nn];
    __syncthreads();
    const int r = tid >> 4, j = tid & 15;
    float mx = NEG_BIG, sm = 0.f;
    #pragma unroll
    for (int q = 0; q < 16; ++q)
        online_upd(mx, sm, ldsR[r][j + q * 16]);
    #pragma unroll
    for (int msk = 1; msk < 16; msk <<= 1)
        online_merge(mx, sm, __shfl_xor(mx, msk), __shfl_xor(sm, msk));
    if (j == 0) { Pm[idx_base + r] = mx; Ps[idx_base + r] = sm; }
    __syncthreads();
}

// ---------------------------------------------------------------------------
// Fused attention-score GEMM:
//   accA[nn] = att[n0+nn, m],  accB[nn] = att[m, n0+nn]
// Writes att (ws), attT (d_out), and 3 stat partial sets [B,16,N]:
//   MrP/SrP: att row stats (reduce accA over m)
//   McP/ScP: att col stats = attT row stats (reduce accB over m)
//   M2P/S2P: att2 row==col stats (reduce accA+accB over m)
// grid: (16 m-chunks, 256 n-blocks, B), block 256.
__global__ LB void att_gemm2(const float* __restrict__ fs, const float* __restrict__ fc,
                             float* __restrict__ att, float* __restrict__ attT,
                             float* __restrict__ McP, float* __restrict__ ScP,
                             float* __restrict__ MrP, float* __restrict__ SrP,
                             float* __restrict__ M2P, float* __restrict__ S2P,
                             int N)
{
    __shared__ float lfs[32][17], lfc[32][17];
    __shared__ float ldsR[16][272];
    const int tid = threadIdx.x;
    const int bx = blockIdx.x;
    const int m  = bx * 256 + tid;
    const int n0 = blockIdx.y * 16;
    const int b  = blockIdx.z;
    for (int i = tid; i < 512; i += 256) {
        const int c = i >> 4, nn = i & 15;
        lfs[c][nn] = fs[((long)b * 32 + c) * N + n0 + nn];
        lfc[c][nn] = fc[((long)b * 32 + c) * N + n0 + nn];
    }
    __syncthreads();
    float accA[16], accB[16];
    #pragma unroll
    for (int i = 0; i < 16; ++i) { accA[i] = 0.f; accB[i] = 0.f; }
    const float* fcp = fc + (long)b * 32 * N + m;
    const float* fsp = fs + (long)b * 32 * N + m;
    #pragma unroll
    for (int c = 0; c < 32; ++c) {
        const float vc = fcp[(long)c * N];
        const float vs = fsp[(long)c * N];
        #pragma unroll
        for (int nn = 0; nn < 16; ++nn) {
            accA[nn] = fmaf(lfs[c][nn], vc, accA[nn]);
            accB[nn] = fmaf(lfc[c][nn], vs, accB[nn]);
        }
    }
    // writes: att rows n0..n0+15 col m; attT row m cols n0..n0+15
    float* op = att + ((long)b * N + n0) * N + m;
    #pragma unroll
    for (int nn = 0; nn < 16; ++nn) op[(long)nn * N] = accA[nn];
    float* opT = attT + ((long)b * N + m) * N + n0;
    #pragma unroll
    for (int q = 0; q < 4; ++q)
        *(float4*)&opT[q * 4] = make_float4(accA[q*4], accA[q*4+1], accA[q*4+2], accA[q*4+3]);

    const long ib = ((long)(b * 16 + bx)) * N + n0;
    rowred(ldsR, accA, MrP, SrP, tid, ib);
    rowred(ldsR, accB, McP, ScP, tid, ib);
    float v2[16];
    #pragma unroll
    for (int nn = 0; nn < 16; ++nn) v2[nn] = accA[nn] + accB[nn];
    rowred(ldsR, v2, M2P, S2P, tid, ib);
}

// ---------------------------------------------------------------------------
// Combine 16 partial (max,sumexp) sets -> final stats (+ optional C2L).
// grid: (N/64, B), block 256 = 64 cols x 4 s-groups.
__global__ LB void stats_comb(const float* __restrict__ Mp, const float* __restrict__ Sp,
                              float* __restrict__ M, float* __restrict__ Sm,
                              float* __restrict__ C2L, int N)
{
    __shared__ float lm[4][64], ls[4][64];
    const int c = threadIdx.x & 63, q = threadIdx.x >> 6;
    const int n = blockIdx.x * 64 + c;
    const int b = blockIdx.y;
    float mx = NEG_BIG, sum = 0.f;
    #pragma unroll
    for (int j = 0; j < 4; ++j) {
        const int s = q * 4 + j;
        online_merge(mx, sum, Mp[((long)(b * 16 + s)) * N + n], Sp[((long)(b * 16 + s)) * N + n]);
    }
    lm[q][c] = mx; ls[q][c] = sum;
    __syncthreads();
    if (q == 0) {
        #pragma unroll
        for (int j = 1; j < 4; ++j) online_merge(mx, sum, lm[j][c], ls[j][c]);
        M[(long)b * N + n]  = mx;
        Sm[(long)b * N + n] = sum;
        if (C2L) C2L[(long)b * N + n] = (mx - LN2 + __logf(sum)) * LOG2E;
    }
}

// ---------------------------------------------------------------------------
// f32 -> bf16 conversion (vectorized).
__global__ LB void to_bf16(const float* __restrict__ in, ushort* __restrict__ out, long n)
{
    const long i = ((long)blockIdx.x * 256 + threadIdx.x) * 4;
    if (i >= n) return;
    const float4 v = *(const float4*)&in[i];
    ushort4 o;
    o.x = bf16rne(v.x); o.y = bf16rne(v.y); o.z = bf16rne(v.z); o.w = bf16rne(v.w);
    *(ushort4*)&out[i] = o;
}

// ---------------------------------------------------------------------------
// MFMA softmax-apply GEMM:
//   part_s[b,row,col] = sum_{k in chunk s} X[b,row,k] * exp(A[b,col,k] - Mv[b,col])
template<int MROWS>
__global__ LB void sm_gemm_mfma(const ushort* __restrict__ Xbf,
                                const float* __restrict__ A,
                                const float* __restrict__ Mv,
                                float* __restrict__ p0, float* __restrict__ p1,
                                int N)
{
    constexpr int RT = MROWS / 32;
    constexpr int TPRA = 256 / MROWS;
    __shared__ ushort ldsA[MROWS][40];
    __shared__ ushort ldsB[32][40];

    const int tid = threadIdx.x;
    const int wave = tid >> 6, lane = tid & 63;
    const int col0 = blockIdx.x * 32;
    const int s = blockIdx.y, b = blockIdx.z;
    const int K0 = s * (N / 2);

    const int scol = tid >> 3, sq = tid & 7;
    const int ar = tid / TPRA;
    const int ak = (tid % TPRA) * (32 / TPRA);
    const int wct = wave & 1;
    const int wrh = wave >> 1;
    const int fr = lane & 15, fg = lane >> 4;

    f32x4 acc[RT];
    #pragma unroll
    for (int i = 0; i < RT; ++i) acc[i] = (f32x4){0.f, 0.f, 0.f, 0.f};

    const float* ab = A + ((long)b * N + col0) * N;
    const ushort* xb = Xbf + (long)b * MROWS * N;
    const float mvl = Mv[(long)b * N + col0 + scol] * LOG2E;

    for (int k0 = K0; k0 < K0 + N / 2; k0 += 32) {
        __syncthreads();
        #pragma unroll
        for (int j = 0; j < 32 / TPRA; j += 8) {
            const short8v av = *(const short8v*)&xb[(long)ar * N + k0 + ak + j];
            *(short8v*)&ldsA[ar][ak + j] = av;
        }
        const float4 v = *(const float4*)&ab[(long)scol * N + k0 + sq * 4];
        ushort4 bfv;
        bfv.x = bf16rne(exp2f(fmaf(v.x, LOG2E, -mvl)));
        bfv.y = bf16rne(exp2f(fmaf(v.y, LOG2E, -mvl)));
        bfv.z = bf16rne(exp2f(fmaf(v.z, LOG2E, -mvl)));
        bfv.w = bf16rne(exp2f(fmaf(v.w, LOG2E, -mvl)));
        *(ushort4*)&ldsB[scol][sq * 4] = bfv;
        __syncthreads();
        const short8v bfrag = *(const short8v*)&ldsB[wct * 16 + fr][8 * fg];
        #pragma unroll
        for (int rt = 0; rt < RT; ++rt) {
            const int row = wrh * (MROWS / 2) + rt * 16 + fr;
            const short8v afrag = *(const short8v*)&ldsA[row][8 * fg];
            acc[rt] = __builtin_amdgcn_mfma_f32_16x16x32_bf16(afrag, bfrag, acc[rt], 0, 0, 0);
        }
    }

    float* pp = (s == 0) ? p0 : p1;
    #pragma unroll
    for (int rt = 0; rt < RT; ++rt) {
        #pragma unroll
        for (int r = 0; r < 4; ++r) {
            const int row = wrh * (MROWS / 2) + rt * 16 + (lane >> 4) * 4 + r;
            const int col = col0 + wct * 16 + (lane & 15);
            pp[((long)b * MROWS + row) * N + col] = acc[rt][r];
        }
    }
}

// Sum 2 K-split partials and divide by per-column softmax denom.
template<int C>
__global__ LB void sm_reduce2(const float* __restrict__ p0, const float* __restrict__ p1,
                              const float* __restrict__ denom, float* __restrict__ outp, int N)
{
    const long idx = (long)blockIdx.x * 256 + threadIdx.x;
    const int m = (int)(idx & (long)(N - 1));
    const int b = (int)(idx / ((long)C * N));
    outp[idx] = (p0[idx] + p1[idx]) / denom[(long)b * N + m];
}

// ---------------------------------------------------------------------------
// Fused: att2 = att + att^T (on the fly), att3 = exp2(att2*log2e - C2L[x]),
// then 3x3 conv + BN + ReLU. Tile 64x32 (halo 66x34). grid: (8192, B).
// Reads ONLY ws att (direct + transposed tiles) -> no overlap with output.
__global__ LB void attmap_conv(const float* __restrict__ att,
                               const float* __restrict__ C2L,
                               const float* __restrict__ w, const float* __restrict__ g,
                               float* __restrict__ out, int N)
{
    __shared__ float tD[34][68];
    __shared__ float tT[66][35];
    __shared__ float ldc[66];
    const int tid = threadIdx.x;
    const int tx = tid & 63, ty = tid >> 6;
    const int x0 = (blockIdx.x & 63) * 64;
    const int y0 = (blockIdx.x >> 6) * 32;
    const int b = blockIdx.y;
    const float* ap = att + (long)b * N * N;
    const float* cp = C2L + (long)b * N;

    if (tid < 66) {
        const int xx = x0 + tid - 1;
        ldc[tid] = ((unsigned)xx < (unsigned)N) ? cp[xx] : 0.f;
    }
    // direct tile: tD[hy][hx] = att[y0+hy-1][x0+hx-1]
    #pragma unroll
    for (int r = 0; r < 9; ++r) {
        const int e = tid + r * 256;
        if (e < 2244) {
            const int hy = e / 66, hx = e % 66;
            const int yy = y0 + hy - 1, xx = x0 + hx - 1;
            float v = 0.f;
            if ((unsigned)yy < (unsigned)N && (unsigned)xx < (unsigned)N)
                v = ap[(long)yy * N + xx];
            tD[hy][hx] = v;
        }
    }
    // transposed tile: tT[hx][hy] = att[x0+hx-1][y0+hy-1] (coalesced 34-runs)
    #pragma unroll
    for (int r = 0; r < 9; ++r) {
        const int e = tid + r * 256;
        if (e < 2244) {
            const int hx = e / 34, hy = e % 34;
            const int yy = y0 + hy - 1, xx = x0 + hx - 1;
            float v = 0.f;
            if ((unsigned)yy < (unsigned)N && (unsigned)xx < (unsigned)N)
                v = ap[(long)xx * N + yy];
            tT[hx][hy] = v;
        }
    }
    __syncthreads();
    // combine + exp2 in place into tD
    #pragma unroll
    for (int r = 0; r < 9; ++r) {
        const int e = tid + r * 256;
        if (e < 2244) {
            const int hy = e / 66, hx = e % 66;
            const int yy = y0 + hy - 1, xx = x0 + hx - 1;
            float v = 0.f;
            if ((unsigned)yy < (unsigned)N && (unsigned)xx < (unsigned)N)
                v = exp2f(fmaf(tD[hy][hx] + tT[hx][hy], LOG2E, -ldc[hx]));
            tD[hy][hx] = v;
        }
    }
    __syncthreads();

    const float scale = g[0] * BN_SCALE, beta = g[1];
    float* ob = out + (long)b * N * N + (long)y0 * N + x0 + tx;
    #pragma unroll
    for (int rr = 0; rr < 8; ++rr) {
        const int ly = ty * 8 + rr;
        float acc = 0.f;
        #pragma unroll
        for (int ky = 0; ky < 3; ++ky)
            #pragma unroll
            for (int kx = 0; kx < 3; ++kx)
                acc = fmaf(w[ky * 3 + kx], tD[ly + ky][tx + kx], acc);
        ob[(long)ly * N] = fmaxf(fmaf(acc, scale, beta), 0.f);
    }
}

// ===========================================================================
extern "C" void kernel_launch(void* const* d_in, const int* in_sizes, int n_in,
                              void* d_out, int out_size, void* d_ws, size_t ws_size,
                              hipStream_t stream)
{
    const float* xs   = (const float*)d_in[0];
    const float* xc   = (const float*)d_in[1];
    const float* w_g1 = (const float*)d_in[2];
    const float* g_g1 = (const float*)d_in[3];
    const float* w_g2 = (const float*)d_in[4];
    const float* g_g2 = (const float*)d_in[5];
    const float* w_ls = (const float*)d_in[6];
    const float* b_ls = (const float*)d_in[7];
    const float* g_ls = (const float*)d_in[8];
    const float* w_lc = (const float*)d_in[9];
    const float* b_lc = (const float*)d_in[10];
    const float* g_lc = (const float*)d_in[11];
    const float* w_c1 = (const float*)d_in[12];
    const float* g_c1 = (const float*)d_in[13];
    const float* w_c2 = (const float*)d_in[14];
    const float* g_c2 = (const float*)d_in[15];
    const float* w_o1 = (const float*)d_in[16];
    const float* g_o1 = (const float*)d_in[17];
    const float* w_o2 = (const float*)d_in[18];
    const float* g_o2 = (const float*)d_in[19];
    const float* w_oa = (const float*)d_in[20];
    const float* g_oa = (const float*)d_in[21];

    const int B = 2, HW = 4096, N = 4096;

    // ---- workspace layout (float offsets) ----
    float* ws = (float*)d_ws;
    float* xs1    = ws;                       // 524288
    float* xc1    = ws + 524288;              // 1048576
    float* fs     = ws + 1572864;             // 262144
    float* fc     = ws + 1835008;             // 262144
    float* McP    = ws + 2097152;             // 131072 (t32 slot lo)
    float* ScP    = ws + 2228224;             // 131072 (t32 slot hi)
    float* t32    = ws + 2097152;             // conv g1/g2 temp (dead before McP)
    float* M2P    = ws + 2359296;             // 131072 (outs_w lo)
    float* S2P    = ws + 2490368;             // 131072 (outs_w hi)
    float* outs_w = ws + 2359296;             // 524288 (written later)
    float* outc_w = ws + 2883584;             // 1048576
    float* gs_w   = ws + 3932160;             // 64
    float* gc_w   = ws + 3932224;             // 64
    float* Mc     = ws + 3932288;             // 8192
    float* Sc     = ws + 3940480;             // 8192
    float* Mr     = ws + 3948672;             // 8192
    float* Sr     = ws + 3956864;             // 8192
    float* M2     = ws + 3965056;             // 8192
    float* S2     = ws + 3973248;             // 8192
    float* MrP    = ws + 3981440;             // 131072 (old Mp slot)
    float* C2L    = ws + 3981440;             // 8192 (after MrP dead)
    float* SrP    = ws + 4112512;             // 131072 (old Sp slot)
    float* att    = ws + 4243584;             // 33554432
    float* cpart  = att;                      // conv partials alias
    float* pg1    = ws + 1572864;             // GEMM partial s=1 (fs.. region)
    ushort* xs1bf = (ushort*)(ws + 2097152);  // t32 slot (after combs)

    // ---- d_out layout ----
    float* out = (float*)d_out;
    float* out_attmap = out;                       // final att_map; attT mid-phase
    float* attT       = out;                       // [B,N,N]
    float* out_s      = out + 33554432;            // 524288
    float* out_c      = out + 34078720;            // 1048576
    float* out_gs     = out + 35127296;            // 64
    float* out_gc     = out + 35127360;            // 64
    float* pg0        = out + 33554432;            // GEMM partial s=0 (dead before out_s)
    ushort* xc1bf     = (ushort*)(out + 34603008); // 1,048,576 ushorts

    const dim3 blk(256);
    const int ICS = 8;

    // global context s/c
    conv3x3_big<<<dim3(4, 4, B * ICS), blk, 0, stream>>>(xs, nullptr, w_g1, nullptr, cpart, 0, 64, 32, ICS);
    conv_combine<<<dim3((B * 32 * HW) / 256), blk, 0, stream>>>(cpart, g_g1, nullptr, t32, 32, ICS);
    gap_kernel<<<dim3(32, B), blk, 0, stream>>>(t32, gs_w, out_gs, 32, HW);
    conv3x3_big<<<dim3(4, 4, B * ICS), blk, 0, stream>>>(xc, nullptr, w_g2, nullptr, cpart, 0, 128, 32, ICS);
    conv_combine<<<dim3((B * 32 * HW) / 256), blk, 0, stream>>>(cpart, g_g2, nullptr, t32, 32, ICS);
    gap_kernel<<<dim3(32, B), blk, 0, stream>>>(t32, gc_w, out_gc, 32, HW);
    // local fusion convs + residual
    conv3x3_big<<<dim3(4, 8, B * ICS), blk, 0, stream>>>(xs, gs_w, w_ls, b_ls, cpart, 32, 64, 64, ICS);
    conv_combine<<<dim3((B * 64 * HW) / 256), blk, 0, stream>>>(cpart, g_ls, xs, xs1, 64, ICS);
    conv3x3_big<<<dim3(4, 16, B * ICS), blk, 0, stream>>>(xc, gc_w, w_lc, b_lc, cpart, 32, 128, 128, ICS);
    conv_combine<<<dim3((B * 128 * HW) / 256), blk, 0, stream>>>(cpart, g_lc, xc, xc1, 128, ICS);
    // attention features
    conv3x3_big<<<dim3(4, 4, B * ICS), blk, 0, stream>>>(xs1, nullptr, w_c1, nullptr, cpart, 0, 64, 32, ICS);
    conv_combine<<<dim3((B * 32 * HW) / 256), blk, 0, stream>>>(cpart, g_c1, nullptr, fs, 32, ICS);
    conv3x3_big<<<dim3(4, 4, B * ICS), blk, 0, stream>>>(xc1, nullptr, w_c2, nullptr, cpart, 0, 128, 32, ICS);
    conv_combine<<<dim3((B * 32 * HW) / 256), blk, 0, stream>>>(cpart, g_c2, nullptr, fc, 32, ICS);
    // fused att GEMM: att, attT, and all three stat partial sets
    att_gemm2<<<dim3(16, 256, B), blk, 0, stream>>>(fs, fc, att, attT,
                                                    McP, ScP, MrP, SrP, M2P, S2P, N);
    stats_comb<<<dim3(64, B), blk, 0, stream>>>(McP, ScP, Mc, Sc, nullptr, N);
    stats_comb<<<dim3(64, B), blk, 0, stream>>>(MrP, SrP, Mr, Sr, nullptr, N);
    stats_comb<<<dim3(64, B), blk, 0, stream>>>(M2P, S2P, M2, S2, C2L, N);
    // outc = xc1 @ rowsoftmax(att)^T  via MFMA
    to_bf16<<<dim3(1024), blk, 0, stream>>>(xc1, xc1bf, (long)B * 128 * N);
    sm_gemm_mfma<128><<<dim3(128, 2, B), blk, 0, stream>>>(xc1bf, att, Mr, pg0, pg1, N);
    sm_reduce2<128><<<dim3((B * 128 * N) / 256), blk, 0, stream>>>(pg0, pg1, Sr, outc_w, N);
    // outs = xs1 @ colsoftmax(att)  via MFMA on attT
    to_bf16<<<dim3(512), blk, 0, stream>>>(xs1, xs1bf, (long)B * 64 * N);
    sm_gemm_mfma<64><<<dim3(128, 2, B), blk, 0, stream>>>(xs1bf, attT, Mc, pg0, pg1, N);
    sm_reduce2<64><<<dim3((B * 64 * N) / 256), blk, 0, stream>>>(pg0, pg1, Sc, outs_w, N);
    // fused att2+att3+conv (reads ws att only; attT dead; writes final map)
    attmap_conv<<<dim3(8192, B), blk, 0, stream>>>(att, C2L, w_oa, g_oa, out_attmap, N);
    // output convs + residuals (att region free again for partials)
    conv3x3_big<<<dim3(4, 8, B * ICS), blk, 0, stream>>>(outs_w, nullptr, w_o1, nullptr, cpart, 0, 64, 64, ICS);
    conv_combine<<<dim3((B * 64 * HW) / 256), blk, 0, stream>>>(cpart, g_o1, xs1, out_s, 64, ICS);
    conv3x3_big<<<dim3(4, 16, B * ICS), blk, 0, stream>>>(outc_w, nullptr, w_o2, nullptr, cpart, 0, 128, 128, ICS);
    conv_combine<<<dim3((B * 128 * HW) / 256), blk, 0, stream>>>(cpart, g_o2, xc1, out_c, 128, ICS);
}

// Round 10
// 839.487 us; speedup vs baseline: 1.3905x; 1.3905x over previous
//
#include <hip/hip_runtime.h>

// AGLI_5703716569604 — round 9: revert fat att_gemm2; one streaming tri_stats
// pass (all 3 stat sets); keep on-the-fly att2 in attmap_conv.
// B=2, ch1=64, ch2=128, H=W=64, N=4096, att [B,4096,4096].

#define LB __launch_bounds__(256)

constexpr float BN_SCALE = 0.99999500003749968f; // 1/sqrt(1+1e-5)
constexpr float NEG_BIG  = -3.402823466e38f;
constexpr float LOG2E    = 1.4426950408889634f;
constexpr float LN2      = 0.6931471805599453f;

typedef __attribute__((ext_vector_type(8))) short short8v;
typedef __attribute__((ext_vector_type(4))) float f32x4;

__device__ __forceinline__ ushort bf16rne(float f) {
    unsigned u = __float_as_uint(f);
    unsigned r = (u + 0x7FFFu + ((u >> 16) & 1u)) >> 16;
    return (ushort)r;
}

__device__ __forceinline__ void online_upd(float& mx, float& sm, float v) {
    if (v > mx) { sm = sm * __expf(mx - v) + 1.f; mx = v; }
    else        { sm += __expf(v - mx); }
}
__device__ __forceinline__ void online_merge(float& mx, float& sm, float m2, float s2) {
    const float mn = fmaxf(mx, m2);
    sm = sm * __expf(mx - mn) + s2 * __expf(m2 - mn);
    mx = mn;
}

// ---------------------------------------------------------------------------
// Stage one 34x34 halo tile (stride 35) for input channel image ib.
__device__ __forceinline__ void stage_tile(const float* __restrict__ ib,
                                           float* __restrict__ buf,
                                           int x0, int y0, int tid)
{
    #pragma unroll
    for (int r = 0; r < 5; ++r) {
        const int e = tid + r * 256;
        if (e < 1156) {
            const int hy = e / 34, hx = e % 34;
            const int yy = y0 + hy - 1, xx = x0 + hx - 1;
            float v = 0.f;
            if ((unsigned)yy < 64u && (unsigned)xx < 64u)
                v = ib[yy * 64 + xx];
            buf[hy * 35 + hx] = v;
        }
    }
}

// ---------------------------------------------------------------------------
// 3x3 conv partial over an ic-chunk (unchanged).
__global__ LB void conv3x3_big(
    const float* __restrict__ in, const float* __restrict__ gconst,
    const float* __restrict__ w, const float* __restrict__ bias,
    float* __restrict__ part, int Cg, int Cin, int Cout, int ICS)
{
    __shared__ float buf[2][34 * 35];
    __shared__ float wg[8][10];
    const int tid = threadIdx.x;
    const int tx = tid & 15, ty = tid >> 4;
    const int x0 = (blockIdx.x & 1) * 32, y0 = (blockIdx.x >> 1) * 32;
    const int oc0 = blockIdx.y * 8;
    const int b = blockIdx.z / ICS, s = blockIdx.z % ICS;
    const int chunk = Cin / ICS;
    const int ic0 = s * chunk;
    const int Ct = Cg + Cin;
    const int HW = 4096;

    float acc[8][4];
    #pragma unroll
    for (int oc = 0; oc < 8; ++oc)
        #pragma unroll
        for (int p = 0; p < 4; ++p) acc[oc][p] = 0.f;

    if (s == 0) {
        if (bias) {
            #pragma unroll
            for (int oc = 0; oc < 8; ++oc) {
                const float bv = bias[oc0 + oc];
                #pragma unroll
                for (int p = 0; p < 4; ++p) acc[oc][p] = bv;
            }
        }
        if (Cg > 0) {
            for (int e = tid; e < 72; e += 256) {
                const int oc = e / 9, k = e % 9;
                float sm = 0.f;
                for (int ic = 0; ic < Cg; ++ic)
                    sm += gconst[b * Cg + ic] * w[((long)(oc0 + oc) * Ct + ic) * 9 + k];
                wg[oc][k] = sm;
            }
            __syncthreads();
            #pragma unroll
            for (int k = 0; k < 9; ++k) {
                const int dy = k / 3 - 1, dx = k % 3 - 1;
                #pragma unroll
                for (int pr = 0; pr < 2; ++pr)
                    #pragma unroll
                    for (int pc = 0; pc < 2; ++pc) {
                        const int yy = y0 + ty * 2 + pr + dy;
                        const int xx = x0 + tx * 2 + pc + dx;
                        if ((unsigned)yy < 64u && (unsigned)xx < 64u) {
                            #pragma unroll
                            for (int oc = 0; oc < 8; ++oc)
                                acc[oc][pr * 2 + pc] += wg[oc][k];
                        }
                    }
            }
        }
    }

    const float* ib = in + ((long)b * Cin + ic0) * HW;
    stage_tile(ib, buf[0], x0, y0, tid);
    __syncthreads();
    int cur = 0;
    for (int i = 0; i < chunk; ++i) {
        if (i + 1 < chunk)
            stage_tile(ib + (long)(i + 1) * HW, buf[cur ^ 1], x0, y0, tid);
        float win[4][4];
        const float* bp = buf[cur] + (ty * 2) * 35 + tx * 2;
        #pragma unroll
        for (int r = 0; r < 4; ++r) {
            const float2 a = *(const float2*)&bp[r * 35];
            const float2 c = *(const float2*)&bp[r * 35 + 2];
            win[r][0] = a.x; win[r][1] = a.y; win[r][2] = c.x; win[r][3] = c.y;
        }
        const float* wq = w + ((long)oc0 * Ct + Cg + ic0 + i) * 9;
        #pragma unroll
        for (int oc = 0; oc < 8; ++oc) {
            const float* wo = wq + (long)oc * Ct * 9;
            #pragma unroll
            for (int dy = 0; dy < 3; ++dy)
                #pragma unroll
                for (int dx = 0; dx < 3; ++dx) {
                    const float wv = wo[dy * 3 + dx];
                    #pragma unroll
                    for (int pr = 0; pr < 2; ++pr)
                        #pragma unroll
                        for (int pc = 0; pc < 2; ++pc)
                            acc[oc][pr * 2 + pc] =
                                fmaf(wv, win[pr + dy][pc + dx], acc[oc][pr * 2 + pc]);
                }
        }
        __syncthreads();
        cur ^= 1;
    }

    #pragma unroll
    for (int oc = 0; oc < 8; ++oc) {
        #pragma unroll
        for (int pr = 0; pr < 2; ++pr) {
            float* q = part + (((long)s * 2 + b) * Cout + oc0 + oc) * (long)HW
                       + (y0 + ty * 2 + pr) * 64 + x0 + tx * 2;
            *(float2*)q = make_float2(acc[oc][pr * 2], acc[oc][pr * 2 + 1]);
        }
    }
}

// ---------------------------------------------------------------------------
__global__ LB void conv_combine(const float* __restrict__ part,
                                const float* __restrict__ bn,
                                const float* __restrict__ residual,
                                float* __restrict__ out,
                                int Cout, int ICS)
{
    const long idx = (long)blockIdx.x * 256 + threadIdx.x;
    const int hw = (int)(idx & 4095);
    const long t = idx >> 12;
    const int c = (int)(t % Cout);
    const int b = (int)(t / Cout);
    float v = 0.f;
    for (int s = 0; s < ICS; ++s)
        v += part[(((long)s * 2 + b) * Cout + c) * 4096 + hw];
    const float scale = bn[c] * BN_SCALE, beta = bn[Cout + c];
    float r = fmaxf(fmaf(v, scale, beta), 0.f);
    if (residual) r += residual[idx];
    out[idx] = r;
}

// ---------------------------------------------------------------------------
__global__ LB void gap_kernel(const float* __restrict__ in,
                              float* __restrict__ o1, float* __restrict__ o2,
                              int C, int HW)
{
    const int c = blockIdx.x, b = blockIdx.y;
    const float* p = in + ((long)b * C + c) * HW;
    float s = 0.f;
    for (int i = threadIdx.x; i < HW; i += 256) s += p[i];
    #pragma unroll
    for (int off = 32; off; off >>= 1) s += __shfl_down(s, off);
    __shared__ float red[4];
    if ((threadIdx.x & 63) == 0) red[threadIdx.x >> 6] = s;
    __syncthreads();
    if (threadIdx.x == 0) {
        const float t = (red[0] + red[1] + red[2] + red[3]) / (float)HW;
        o1[b * C + c] = t;
        o2[b * C + c] = t;
    }
}

// ---------------------------------------------------------------------------
// att[b,n,m] = sum_c fs[b,c,n] * fc[b,c,m], C=32. Also writes attT[b,m,n].
__global__ LB void att_gemm(const float* __restrict__ fs, const float* __restrict__ fc,
                            float* __restrict__ att, float* __restrict__ attT, int N)
{
    __shared__ float lfs[32][17];
    const int tid = threadIdx.x;
    const int m  = blockIdx.x * 256 + tid;
    const int n0 = blockIdx.y * 16;
    const int b  = blockIdx.z;
    for (int i = tid; i < 32 * 16; i += 256) {
        const int c = i >> 4, nn = i & 15;
        lfs[c][nn] = fs[((long)b * 32 + c) * N + n0 + nn];
    }
    __syncthreads();
    float acc[16];
    #pragma unroll
    for (int i = 0; i < 16; ++i) acc[i] = 0.f;
    const float* fcp = fc + (long)b * 32 * N + m;
    #pragma unroll
    for (int c = 0; c < 32; ++c) {
        const float f = fcp[(long)c * N];
        #pragma unroll
        for (int nn = 0; nn < 16; ++nn) acc[nn] = fmaf(lfs[c][nn], f, acc[nn]);
    }
    float* op = att + ((long)b * N + n0) * N + m;
    #pragma unroll
    for (int nn = 0; nn < 16; ++nn) op[(long)nn * N] = acc[nn];
    float* opT = attT + ((long)b * N + m) * N + n0;
    #pragma unroll
    for (int q = 0; q < 4; ++q)
        *(float4*)&opT[q * 4] = make_float4(acc[q*4], acc[q*4+1], acc[q*4+2], acc[q*4+3]);
}

// ---------------------------------------------------------------------------
// ONE streaming pass over att+attT producing all 3 stat partial sets [B,32,N]:
//   McP/ScP: col-stats of att   (softmax over n, per column m)
//   MrP/SrP: col-stats of attT  == row-stats of att (per row m)
//   M2P/S2P: col-stats of att+attT == att2 stats (symmetric)
// grid: (N/64, 32, B), block 256 = 64 cols x 4 row-groups (chain 32).
__global__ LB void tri_stats(const float* __restrict__ att, const float* __restrict__ attT,
                             float* __restrict__ McP, float* __restrict__ ScP,
                             float* __restrict__ MrP, float* __restrict__ SrP,
                             float* __restrict__ M2P, float* __restrict__ S2P, int N)
{
    __shared__ float lm[3][4][64], ls[3][4][64];
    const int c = threadIdx.x & 63, q = threadIdx.x >> 6;
    const int m = blockIdx.x * 64 + c;
    const int y = blockIdx.y, b = blockIdx.z;
    const long base = (long)b * N * N + ((long)y * 128 + q) * N + m;
    float mc = NEG_BIG, sc = 0.f, mr = NEG_BIG, sr = 0.f, m2 = NEG_BIG, s2 = 0.f;
    for (int r = 0; r < 32; ++r) {
        const long off = base + (long)r * 4 * N;
        const float a = att[off];
        const float t = attT[off];
        online_upd(mc, sc, a);
        online_upd(mr, sr, t);
        online_upd(m2, s2, a + t);
    }
    lm[0][q][c] = mc; ls[0][q][c] = sc;
    lm[1][q][c] = mr; ls[1][q][c] = sr;
    lm[2][q][c] = m2; ls[2][q][c] = s2;
    __syncthreads();
    if (q < 3) {
        float M = lm[q][0][c], S = ls[q][0][c];
        #pragma unroll
        for (int j = 1; j < 4; ++j) online_merge(M, S, lm[q][j][c], ls[q][j][c]);
        float* Pm = (q == 0) ? McP : ((q == 1) ? MrP : M2P);
        float* Ps = (q == 0) ? ScP : ((q == 1) ? SrP : S2P);
        Pm[((long)(b * 32 + y)) * N + m] = M;
        Ps[((long)(b * 32 + y)) * N + m] = S;
    }
}

// ---------------------------------------------------------------------------
// Combine 32 partial (max,sumexp) sets -> final stats (+ optional C2L).
// grid: (N/64, B), block 256 = 64 cols x 4 s-groups of 8.
__global__ LB void stats_comb32(const float* __restrict__ Mp, const float* __restrict__ Sp,
                                float* __restrict__ M, float* __restrict__ Sm,
                                float* __restrict__ C2L, int N)
{
    __shared__ float lm[4][64], ls[4][64];
    const int c = threadIdx.x & 63, q = threadIdx.x >> 6;
    const int n = blockIdx.x * 64 + c;
    const int b = blockIdx.y;
    float mx = NEG_BIG, sum = 0.f;
    #pragma unroll
    for (int j = 0; j < 8; ++j) {
        const int s = q * 8 + j;
        online_merge(mx, sum, Mp[((long)(b * 32 + s)) * N + n], Sp[((long)(b * 32 + s)) * N + n]);
    }
    lm[q][c] = mx; ls[q][c] = sum;
    __syncthreads();
    if (q == 0) {
        #pragma unroll
        for (int j = 1; j < 4; ++j) online_merge(mx, sum, lm[j][c], ls[j][c]);
        M[(long)b * N + n]  = mx;
        Sm[(long)b * N + n] = sum;
        if (C2L) C2L[(long)b * N + n] = (mx - LN2 + __logf(sum)) * LOG2E;
    }
}

// ---------------------------------------------------------------------------
// f32 -> bf16 conversion (vectorized).
__global__ LB void to_bf16(const float* __restrict__ in, ushort* __restrict__ out, long n)
{
    const long i = ((long)blockIdx.x * 256 + threadIdx.x) * 4;
    if (i >= n) return;
    const float4 v = *(const float4*)&in[i];
    ushort4 o;
    o.x = bf16rne(v.x); o.y = bf16rne(v.y); o.z = bf16rne(v.z); o.w = bf16rne(v.w);
    *(ushort4*)&out[i] = o;
}

// ---------------------------------------------------------------------------
// MFMA softmax-apply GEMM:
//   part_s[b,row,col] = sum_{k in chunk s} X[b,row,k] * exp(A[b,col,k] - Mv[b,col])
template<int MROWS>
__global__ LB void sm_gemm_mfma(const ushort* __restrict__ Xbf,
                                const float* __restrict__ A,
                                const float* __restrict__ Mv,
                                float* __restrict__ p0, float* __restrict__ p1,
                                int N)
{
    constexpr int RT = MROWS / 32;
    constexpr int TPRA = 256 / MROWS;
    __shared__ ushort ldsA[MROWS][40];
    __shared__ ushort ldsB[32][40];

    const int tid = threadIdx.x;
    const int wave = tid >> 6, lane = tid & 63;
    const int col0 = blockIdx.x * 32;
    const int s = blockIdx.y, b = blockIdx.z;
    const int K0 = s * (N / 2);

    const int scol = tid >> 3, sq = tid & 7;
    const int ar = tid / TPRA;
    const int ak = (tid % TPRA) * (32 / TPRA);
    const int wct = wave & 1;
    const int wrh = wave >> 1;
    const int fr = lane & 15, fg = lane >> 4;

    f32x4 acc[RT];
    #pragma unroll
    for (int i = 0; i < RT; ++i) acc[i] = (f32x4){0.f, 0.f, 0.f, 0.f};

    const float* ab = A + ((long)b * N + col0) * N;
    const ushort* xb = Xbf + (long)b * MROWS * N;
    const float mvl = Mv[(long)b * N + col0 + scol] * LOG2E;

    for (int k0 = K0; k0 < K0 + N / 2; k0 += 32) {
        __syncthreads();
        #pragma unroll
        for (int j = 0; j < 32 / TPRA; j += 8) {
            const short8v av = *(const short8v*)&xb[(long)ar * N + k0 + ak + j];
            *(short8v*)&ldsA[ar][ak + j] = av;
        }
        const float4 v = *(const float4*)&ab[(long)scol * N + k0 + sq * 4];
        ushort4 bfv;
        bfv.x = bf16rne(exp2f(fmaf(v.x, LOG2E, -mvl)));
        bfv.y = bf16rne(exp2f(fmaf(v.y, LOG2E, -mvl)));
        bfv.z = bf16rne(exp2f(fmaf(v.z, LOG2E, -mvl)));
        bfv.w = bf16rne(exp2f(fmaf(v.w, LOG2E, -mvl)));
        *(ushort4*)&ldsB[scol][sq * 4] = bfv;
        __syncthreads();
        const short8v bfrag = *(const short8v*)&ldsB[wct * 16 + fr][8 * fg];
        #pragma unroll
        for (int rt = 0; rt < RT; ++rt) {
            const int row = wrh * (MROWS / 2) + rt * 16 + fr;
            const short8v afrag = *(const short8v*)&ldsA[row][8 * fg];
            acc[rt] = __builtin_amdgcn_mfma_f32_16x16x32_bf16(afrag, bfrag, acc[rt], 0, 0, 0);
        }
    }

    float* pp = (s == 0) ? p0 : p1;
    #pragma unroll
    for (int rt = 0; rt < RT; ++rt) {
        #pragma unroll
        for (int r = 0; r < 4; ++r) {
            const int row = wrh * (MROWS / 2) + rt * 16 + (lane >> 4) * 4 + r;
            const int col = col0 + wct * 16 + (lane & 15);
            pp[((long)b * MROWS + row) * N + col] = acc[rt][r];
        }
    }
}

// Sum 2 K-split partials and divide by per-column softmax denom.
template<int C>
__global__ LB void sm_reduce2(const float* __restrict__ p0, const float* __restrict__ p1,
                              const float* __restrict__ denom, float* __restrict__ outp, int N)
{
    const long idx = (long)blockIdx.x * 256 + threadIdx.x;
    const int m = (int)(idx & (long)(N - 1));
    const int b = (int)(idx / ((long)C * N));
    outp[idx] = (p0[idx] + p1[idx]) / denom[(long)b * N + m];
}

// ---------------------------------------------------------------------------
// Fused: att2 = att + att^T (on the fly), att3 = exp2(att2*log2e - C2L[x]),
// then 3x3 conv + BN + ReLU. Tile 64x32 (halo 66x34). grid: (8192, B).
// Reads ONLY ws att (direct + transposed tiles) -> no overlap with output.
__global__ LB void attmap_conv(const float* __restrict__ att,
                               const float* __restrict__ C2L,
                               const float* __restrict__ w, const float* __restrict__ g,
                               float* __restrict__ out, int N)
{
    __shared__ float tD[34][68];
    __shared__ float tT[66][35];
    __shared__ float ldc[66];
    const int tid = threadIdx.x;
    const int tx = tid & 63, ty = tid >> 6;
    const int x0 = (blockIdx.x & 63) * 64;
    const int y0 = (blockIdx.x >> 6) * 32;
    const int b = blockIdx.y;
    const float* ap = att + (long)b * N * N;
    const float* cp = C2L + (long)b * N;

    if (tid < 66) {
        const int xx = x0 + tid - 1;
        ldc[tid] = ((unsigned)xx < (unsigned)N) ? cp[xx] : 0.f;
    }
    #pragma unroll
    for (int r = 0; r < 9; ++r) {
        const int e = tid + r * 256;
        if (e < 2244) {
            const int hy = e / 66, hx = e % 66;
            const int yy = y0 + hy - 1, xx = x0 + hx - 1;
            float v = 0.f;
            if ((unsigned)yy < (unsigned)N && (unsigned)xx < (unsigned)N)
                v = ap[(long)yy * N + xx];
            tD[hy][hx] = v;
        }
    }
    #pragma unroll
    for (int r = 0; r < 9; ++r) {
        const int e = tid + r * 256;
        if (e < 2244) {
            const int hx = e / 34, hy = e % 34;
            const int yy = y0 + hy - 1, xx = x0 + hx - 1;
            float v = 0.f;
            if ((unsigned)yy < (unsigned)N && (unsigned)xx < (unsigned)N)
                v = ap[(long)xx * N + yy];
            tT[hx][hy] = v;
        }
    }
    __syncthreads();
    #pragma unroll
    for (int r = 0; r < 9; ++r) {
        const int e = tid + r * 256;
        if (e < 2244) {
            const int hy = e / 66, hx = e % 66;
            const int yy = y0 + hy - 1, xx = x0 + hx - 1;
            float v = 0.f;
            if ((unsigned)yy < (unsigned)N && (unsigned)xx < (unsigned)N)
                v = exp2f(fmaf(tD[hy][hx] + tT[hx][hy], LOG2E, -ldc[hx]));
            tD[hy][hx] = v;
        }
    }
    __syncthreads();

    const float scale = g[0] * BN_SCALE, beta = g[1];
    float* ob = out + (long)b * N * N + (long)y0 * N + x0 + tx;
    #pragma unroll
    for (int rr = 0; rr < 8; ++rr) {
        const int ly = ty * 8 + rr;
        float acc = 0.f;
        #pragma unroll
        for (int ky = 0; ky < 3; ++ky)
            #pragma unroll
            for (int kx = 0; kx < 3; ++kx)
                acc = fmaf(w[ky * 3 + kx], tD[ly + ky][tx + kx], acc);
        ob[(long)ly * N] = fmaxf(fmaf(acc, scale, beta), 0.f);
    }
}

// ===========================================================================
extern "C" void kernel_launch(void* const* d_in, const int* in_sizes, int n_in,
                              void* d_out, int out_size, void* d_ws, size_t ws_size,
                              hipStream_t stream)
{
    const float* xs   = (const float*)d_in[0];
    const float* xc   = (const float*)d_in[1];
    const float* w_g1 = (const float*)d_in[2];
    const float* g_g1 = (const float*)d_in[3];
    const float* w_g2 = (const float*)d_in[4];
    const float* g_g2 = (const float*)d_in[5];
    const float* w_ls = (const float*)d_in[6];
    const float* b_ls = (const float*)d_in[7];
    const float* g_ls = (const float*)d_in[8];
    const float* w_lc = (const float*)d_in[9];
    const float* b_lc = (const float*)d_in[10];
    const float* g_lc = (const float*)d_in[11];
    const float* w_c1 = (const float*)d_in[12];
    const float* g_c1 = (const float*)d_in[13];
    const float* w_c2 = (const float*)d_in[14];
    const float* g_c2 = (const float*)d_in[15];
    const float* w_o1 = (const float*)d_in[16];
    const float* g_o1 = (const float*)d_in[17];
    const float* w_o2 = (const float*)d_in[18];
    const float* g_o2 = (const float*)d_in[19];
    const float* w_oa = (const float*)d_in[20];
    const float* g_oa = (const float*)d_in[21];

    const int B = 2, HW = 4096, N = 4096;

    // ---- workspace layout (float offsets) ----
    float* ws = (float*)d_ws;
    float* xs1    = ws;                       // 524288
    float* xc1    = ws + 524288;              // 1048576
    float* fs     = ws + 1572864;             // 262144 (conv phase)
    float* fc     = ws + 1835008;             // 262144
    float* t32    = ws + 2097152;             // 262144 (conv phase)
    // stat partials [B,32,N] = 262144 each (after att_gemm, fs/fc/t32 dead):
    float* McP    = ws + 1572864;
    float* ScP    = ws + 1835008;
    float* MrP    = ws + 2097152;
    float* SrP    = ws + 2359296;
    float* M2P    = ws + 2621440;
    float* S2P    = ws + 2883584;
    // GEMM phase (partials dead after combines):
    float* pg1    = ws + 1572864;             // K-split partial s=1 (<=1048576)
    ushort* xs1bf = (ushort*)(ws + 2621440);  // 524288 ushorts = 262144 floats
    float* outs_w = ws + 2359296;             // 524288 (written by reduce64)
    float* outc_w = ws + 2883584;             // 1048576 (written by reduce128)
    float* gs_w   = ws + 3932160;             // 64
    float* gc_w   = ws + 3932224;             // 64
    float* Mc     = ws + 3932288;             // 8192
    float* Sc     = ws + 3940480;             // 8192
    float* Mr     = ws + 3948672;             // 8192
    float* Sr     = ws + 3956864;             // 8192
    float* M2     = ws + 3965056;             // 8192
    float* S2     = ws + 3973248;             // 8192
    float* C2L    = ws + 3981440;             // 8192
    float* att    = ws + 4243584;             // 33554432
    float* cpart  = att;                      // conv partials alias

    // ---- d_out layout ----
    float* out = (float*)d_out;
    float* out_attmap = out;                       // final att_map; attT mid-phase
    float* attT       = out;                       // [B,N,N]
    float* out_s      = out + 33554432;            // 524288
    float* out_c      = out + 34078720;            // 1048576
    float* out_gs     = out + 35127296;            // 64
    float* out_gc     = out + 35127360;            // 64
    float* pg0        = out + 33554432;            // GEMM partial s=0 (dead before out_s)
    ushort* xc1bf     = (ushort*)(out + 34603008); // dead before out_c final write

    const dim3 blk(256);
    const int ICS = 8;

    // global context s/c
    conv3x3_big<<<dim3(4, 4, B * ICS), blk, 0, stream>>>(xs, nullptr, w_g1, nullptr, cpart, 0, 64, 32, ICS);
    conv_combine<<<dim3((B * 32 * HW) / 256), blk, 0, stream>>>(cpart, g_g1, nullptr, t32, 32, ICS);
    gap_kernel<<<dim3(32, B), blk, 0, stream>>>(t32, gs_w, out_gs, 32, HW);
    conv3x3_big<<<dim3(4, 4, B * ICS), blk, 0, stream>>>(xc, nullptr, w_g2, nullptr, cpart, 0, 128, 32, ICS);
    conv_combine<<<dim3((B * 32 * HW) / 256), blk, 0, stream>>>(cpart, g_g2, nullptr, t32, 32, ICS);
    gap_kernel<<<dim3(32, B), blk, 0, stream>>>(t32, gc_w, out_gc, 32, HW);
    // local fusion convs + residual
    conv3x3_big<<<dim3(4, 8, B * ICS), blk, 0, stream>>>(xs, gs_w, w_ls, b_ls, cpart, 32, 64, 64, ICS);
    conv_combine<<<dim3((B * 64 * HW) / 256), blk, 0, stream>>>(cpart, g_ls, xs, xs1, 64, ICS);
    conv3x3_big<<<dim3(4, 16, B * ICS), blk, 0, stream>>>(xc, gc_w, w_lc, b_lc, cpart, 32, 128, 128, ICS);
    conv_combine<<<dim3((B * 128 * HW) / 256), blk, 0, stream>>>(cpart, g_lc, xc, xc1, 128, ICS);
    // attention features
    conv3x3_big<<<dim3(4, 4, B * ICS), blk, 0, stream>>>(xs1, nullptr, w_c1, nullptr, cpart, 0, 64, 32, ICS);
    conv_combine<<<dim3((B * 32 * HW) / 256), blk, 0, stream>>>(cpart, g_c1, nullptr, fs, 32, ICS);
    conv3x3_big<<<dim3(4, 4, B * ICS), blk, 0, stream>>>(xc1, nullptr, w_c2, nullptr, cpart, 0, 128, 32, ICS);
    conv_combine<<<dim3((B * 32 * HW) / 256), blk, 0, stream>>>(cpart, g_c2, nullptr, fc, 32, ICS);
    // att = fs^T fc  (+ attT into d_out scratch)
    att_gemm<<<dim3(16, 256, B), blk, 0, stream>>>(fs, fc, att, attT, N);
    // ONE streaming pass: all three stat partial sets
    tri_stats<<<dim3(64, 32, B), blk, 0, stream>>>(att, attT, McP, ScP, MrP, SrP, M2P, S2P, N);
    stats_comb32<<<dim3(64, B), blk, 0, stream>>>(McP, ScP, Mc, Sc, nullptr, N);
    stats_comb32<<<dim3(64, B), blk, 0, stream>>>(MrP, SrP, Mr, Sr, nullptr, N);
    stats_comb32<<<dim3(64, B), blk, 0, stream>>>(M2P, S2P, M2, S2, C2L, N);
    // bf16 conversions (partials dead now)
    to_bf16<<<dim3(1024), blk, 0, stream>>>(xc1, xc1bf, (long)B * 128 * N);
    to_bf16<<<dim3(512), blk, 0, stream>>>(xs1, xs1bf, (long)B * 64 * N);
    // outc = xc1 @ rowsoftmax(att)^T  via MFMA
    sm_gemm_mfma<128><<<dim3(128, 2, B), blk, 0, stream>>>(xc1bf, att, Mr, pg0, pg1, N);
    sm_reduce2<128><<<dim3((B * 128 * N) / 256), blk, 0, stream>>>(pg0, pg1, Sr, outc_w, N);
    // outs = xs1 @ colsoftmax(att)  via MFMA on attT
    sm_gemm_mfma<64><<<dim3(128, 2, B), blk, 0, stream>>>(xs1bf, attT, Mc, pg0, pg1, N);
    sm_reduce2<64><<<dim3((B * 64 * N) / 256), blk, 0, stream>>>(pg0, pg1, Sc, outs_w, N);
    // fused att2+att3+conv (reads ws att only; attT dead; writes final map)
    attmap_conv<<<dim3(8192, B), blk, 0, stream>>>(att, C2L, w_oa, g_oa, out_attmap, N);
    // output convs + residuals (att region free again for partials)
    conv3x3_big<<<dim3(4, 8, B * ICS), blk, 0, stream>>>(outs_w, nullptr, w_o1, nullptr, cpart, 0, 64, 64, ICS);
    conv_combine<<<dim3((B * 64 * HW) / 256), blk, 0, stream>>>(cpart, g_o1, xs1, out_s, 64, ICS);
    conv3x3_big<<<dim3(4, 16, B * ICS), blk, 0, stream>>>(outc_w, nullptr, w_o2, nullptr, cpart, 0, 128, 128, ICS);
    conv_combine<<<dim3((B * 128 * HW) / 256), blk, 0, stream>>>(cpart, g_o2, xc1, out_c, 128, ICS);
}

// Round 11
// 831.268 us; speedup vs baseline: 1.4042x; 1.0099x over previous
//
#include <hip/hip_runtime.h>

// AGLI_5703716569604 — round 10: attT moved to ws (ws_size ≥536MB per fill
// counter); attmap_conv reads att+attT fully coalesced, single staging pass.
// B=2, ch1=64, ch2=128, H=W=64, N=4096, att [B,4096,4096].

#define LB __launch_bounds__(256)

constexpr float BN_SCALE = 0.99999500003749968f; // 1/sqrt(1+1e-5)
constexpr float NEG_BIG  = -3.402823466e38f;
constexpr float LOG2E    = 1.4426950408889634f;
constexpr float LN2      = 0.6931471805599453f;

typedef __attribute__((ext_vector_type(8))) short short8v;
typedef __attribute__((ext_vector_type(4))) float f32x4;

__device__ __forceinline__ ushort bf16rne(float f) {
    unsigned u = __float_as_uint(f);
    unsigned r = (u + 0x7FFFu + ((u >> 16) & 1u)) >> 16;
    return (ushort)r;
}

__device__ __forceinline__ void online_upd(float& mx, float& sm, float v) {
    if (v > mx) { sm = sm * __expf(mx - v) + 1.f; mx = v; }
    else        { sm += __expf(v - mx); }
}
__device__ __forceinline__ void online_merge(float& mx, float& sm, float m2, float s2) {
    const float mn = fmaxf(mx, m2);
    sm = sm * __expf(mx - mn) + s2 * __expf(m2 - mn);
    mx = mn;
}

// ---------------------------------------------------------------------------
// Stage one 34x34 halo tile (stride 35) for input channel image ib.
__device__ __forceinline__ void stage_tile(const float* __restrict__ ib,
                                           float* __restrict__ buf,
                                           int x0, int y0, int tid)
{
    #pragma unroll
    for (int r = 0; r < 5; ++r) {
        const int e = tid + r * 256;
        if (e < 1156) {
            const int hy = e / 34, hx = e % 34;
            const int yy = y0 + hy - 1, xx = x0 + hx - 1;
            float v = 0.f;
            if ((unsigned)yy < 64u && (unsigned)xx < 64u)
                v = ib[yy * 64 + xx];
            buf[hy * 35 + hx] = v;
        }
    }
}

// ---------------------------------------------------------------------------
// 3x3 conv partial over an ic-chunk (unchanged).
__global__ LB void conv3x3_big(
    const float* __restrict__ in, const float* __restrict__ gconst,
    const float* __restrict__ w, const float* __restrict__ bias,
    float* __restrict__ part, int Cg, int Cin, int Cout, int ICS)
{
    __shared__ float buf[2][34 * 35];
    __shared__ float wg[8][10];
    const int tid = threadIdx.x;
    const int tx = tid & 15, ty = tid >> 4;
    const int x0 = (blockIdx.x & 1) * 32, y0 = (blockIdx.x >> 1) * 32;
    const int oc0 = blockIdx.y * 8;
    const int b = blockIdx.z / ICS, s = blockIdx.z % ICS;
    const int chunk = Cin / ICS;
    const int ic0 = s * chunk;
    const int Ct = Cg + Cin;
    const int HW = 4096;

    float acc[8][4];
    #pragma unroll
    for (int oc = 0; oc < 8; ++oc)
        #pragma unroll
        for (int p = 0; p < 4; ++p) acc[oc][p] = 0.f;

    if (s == 0) {
        if (bias) {
            #pragma unroll
            for (int oc = 0; oc < 8; ++oc) {
                const float bv = bias[oc0 + oc];
                #pragma unroll
                for (int p = 0; p < 4; ++p) acc[oc][p] = bv;
            }
        }
        if (Cg > 0) {
            for (int e = tid; e < 72; e += 256) {
                const int oc = e / 9, k = e % 9;
                float sm = 0.f;
                for (int ic = 0; ic < Cg; ++ic)
                    sm += gconst[b * Cg + ic] * w[((long)(oc0 + oc) * Ct + ic) * 9 + k];
                wg[oc][k] = sm;
            }
            __syncthreads();
            #pragma unroll
            for (int k = 0; k < 9; ++k) {
                const int dy = k / 3 - 1, dx = k % 3 - 1;
                #pragma unroll
                for (int pr = 0; pr < 2; ++pr)
                    #pragma unroll
                    for (int pc = 0; pc < 2; ++pc) {
                        const int yy = y0 + ty * 2 + pr + dy;
                        const int xx = x0 + tx * 2 + pc + dx;
                        if ((unsigned)yy < 64u && (unsigned)xx < 64u) {
                            #pragma unroll
                            for (int oc = 0; oc < 8; ++oc)
                                acc[oc][pr * 2 + pc] += wg[oc][k];
                        }
                    }
            }
        }
    }

    const float* ib = in + ((long)b * Cin + ic0) * HW;
    stage_tile(ib, buf[0], x0, y0, tid);
    __syncthreads();
    int cur = 0;
    for (int i = 0; i < chunk; ++i) {
        if (i + 1 < chunk)
            stage_tile(ib + (long)(i + 1) * HW, buf[cur ^ 1], x0, y0, tid);
        float win[4][4];
        const float* bp = buf[cur] + (ty * 2) * 35 + tx * 2;
        #pragma unroll
        for (int r = 0; r < 4; ++r) {
            const float2 a = *(const float2*)&bp[r * 35];
            const float2 c = *(const float2*)&bp[r * 35 + 2];
            win[r][0] = a.x; win[r][1] = a.y; win[r][2] = c.x; win[r][3] = c.y;
        }
        const float* wq = w + ((long)oc0 * Ct + Cg + ic0 + i) * 9;
        #pragma unroll
        for (int oc = 0; oc < 8; ++oc) {
            const float* wo = wq + (long)oc * Ct * 9;
            #pragma unroll
            for (int dy = 0; dy < 3; ++dy)
                #pragma unroll
                for (int dx = 0; dx < 3; ++dx) {
                    const float wv = wo[dy * 3 + dx];
                    #pragma unroll
                    for (int pr = 0; pr < 2; ++pr)
                        #pragma unroll
                        for (int pc = 0; pc < 2; ++pc)
                            acc[oc][pr * 2 + pc] =
                                fmaf(wv, win[pr + dy][pc + dx], acc[oc][pr * 2 + pc]);
                }
        }
        __syncthreads();
        cur ^= 1;
    }

    #pragma unroll
    for (int oc = 0; oc < 8; ++oc) {
        #pragma unroll
        for (int pr = 0; pr < 2; ++pr) {
            float* q = part + (((long)s * 2 + b) * Cout + oc0 + oc) * (long)HW
                       + (y0 + ty * 2 + pr) * 64 + x0 + tx * 2;
            *(float2*)q = make_float2(acc[oc][pr * 2], acc[oc][pr * 2 + 1]);
        }
    }
}

// ---------------------------------------------------------------------------
__global__ LB void conv_combine(const float* __restrict__ part,
                                const float* __restrict__ bn,
                                const float* __restrict__ residual,
                                float* __restrict__ out,
                                int Cout, int ICS)
{
    const long idx = (long)blockIdx.x * 256 + threadIdx.x;
    const int hw = (int)(idx & 4095);
    const long t = idx >> 12;
    const int c = (int)(t % Cout);
    const int b = (int)(t / Cout);
    float v = 0.f;
    for (int s = 0; s < ICS; ++s)
        v += part[(((long)s * 2 + b) * Cout + c) * 4096 + hw];
    const float scale = bn[c] * BN_SCALE, beta = bn[Cout + c];
    float r = fmaxf(fmaf(v, scale, beta), 0.f);
    if (residual) r += residual[idx];
    out[idx] = r;
}

// ---------------------------------------------------------------------------
__global__ LB void gap_kernel(const float* __restrict__ in,
                              float* __restrict__ o1, float* __restrict__ o2,
                              int C, int HW)
{
    const int c = blockIdx.x, b = blockIdx.y;
    const float* p = in + ((long)b * C + c) * HW;
    float s = 0.f;
    for (int i = threadIdx.x; i < HW; i += 256) s += p[i];
    #pragma unroll
    for (int off = 32; off; off >>= 1) s += __shfl_down(s, off);
    __shared__ float red[4];
    if ((threadIdx.x & 63) == 0) red[threadIdx.x >> 6] = s;
    __syncthreads();
    if (threadIdx.x == 0) {
        const float t = (red[0] + red[1] + red[2] + red[3]) / (float)HW;
        o1[b * C + c] = t;
        o2[b * C + c] = t;
    }
}

// ---------------------------------------------------------------------------
// att[b,n,m] = sum_c fs[b,c,n] * fc[b,c,m], C=32. Also writes attT[b,m,n].
__global__ LB void att_gemm(const float* __restrict__ fs, const float* __restrict__ fc,
                            float* __restrict__ att, float* __restrict__ attT, int N)
{
    __shared__ float lfs[32][17];
    const int tid = threadIdx.x;
    const int m  = blockIdx.x * 256 + tid;
    const int n0 = blockIdx.y * 16;
    const int b  = blockIdx.z;
    for (int i = tid; i < 32 * 16; i += 256) {
        const int c = i >> 4, nn = i & 15;
        lfs[c][nn] = fs[((long)b * 32 + c) * N + n0 + nn];
    }
    __syncthreads();
    float acc[16];
    #pragma unroll
    for (int i = 0; i < 16; ++i) acc[i] = 0.f;
    const float* fcp = fc + (long)b * 32 * N + m;
    #pragma unroll
    for (int c = 0; c < 32; ++c) {
        const float f = fcp[(long)c * N];
        #pragma unroll
        for (int nn = 0; nn < 16; ++nn) acc[nn] = fmaf(lfs[c][nn], f, acc[nn]);
    }
    float* op = att + ((long)b * N + n0) * N + m;
    #pragma unroll
    for (int nn = 0; nn < 16; ++nn) op[(long)nn * N] = acc[nn];
    float* opT = attT + ((long)b * N + m) * N + n0;
    #pragma unroll
    for (int q = 0; q < 4; ++q)
        *(float4*)&opT[q * 4] = make_float4(acc[q*4], acc[q*4+1], acc[q*4+2], acc[q*4+3]);
}

// ---------------------------------------------------------------------------
// ONE streaming pass over att+attT producing all 3 stat partial sets [B,32,N].
__global__ LB void tri_stats(const float* __restrict__ att, const float* __restrict__ attT,
                             float* __restrict__ McP, float* __restrict__ ScP,
                             float* __restrict__ MrP, float* __restrict__ SrP,
                             float* __restrict__ M2P, float* __restrict__ S2P, int N)
{
    __shared__ float lm[3][4][64], ls[3][4][64];
    const int c = threadIdx.x & 63, q = threadIdx.x >> 6;
    const int m = blockIdx.x * 64 + c;
    const int y = blockIdx.y, b = blockIdx.z;
    const long base = (long)b * N * N + ((long)y * 128 + q) * N + m;
    float mc = NEG_BIG, sc = 0.f, mr = NEG_BIG, sr = 0.f, m2 = NEG_BIG, s2 = 0.f;
    for (int r = 0; r < 32; ++r) {
        const long off = base + (long)r * 4 * N;
        const float a = att[off];
        const float t = attT[off];
        online_upd(mc, sc, a);
        online_upd(mr, sr, t);
        online_upd(m2, s2, a + t);
    }
    lm[0][q][c] = mc; ls[0][q][c] = sc;
    lm[1][q][c] = mr; ls[1][q][c] = sr;
    lm[2][q][c] = m2; ls[2][q][c] = s2;
    __syncthreads();
    if (q < 3) {
        float M = lm[q][0][c], S = ls[q][0][c];
        #pragma unroll
        for (int j = 1; j < 4; ++j) online_merge(M, S, lm[q][j][c], ls[q][j][c]);
        float* Pm = (q == 0) ? McP : ((q == 1) ? MrP : M2P);
        float* Ps = (q == 0) ? ScP : ((q == 1) ? SrP : S2P);
        Pm[((long)(b * 32 + y)) * N + m] = M;
        Ps[((long)(b * 32 + y)) * N + m] = S;
    }
}

// ---------------------------------------------------------------------------
// Combine 32 partial (max,sumexp) sets -> final stats (+ optional C2L).
__global__ LB void stats_comb32(const float* __restrict__ Mp, const float* __restrict__ Sp,
                                float* __restrict__ M, float* __restrict__ Sm,
                                float* __restrict__ C2L, int N)
{
    __shared__ float lm[4][64], ls[4][64];
    const int c = threadIdx.x & 63, q = threadIdx.x >> 6;
    const int n = blockIdx.x * 64 + c;
    const int b = blockIdx.y;
    float mx = NEG_BIG, sum = 0.f;
    #pragma unroll
    for (int j = 0; j < 8; ++j) {
        const int s = q * 8 + j;
        online_merge(mx, sum, Mp[((long)(b * 32 + s)) * N + n], Sp[((long)(b * 32 + s)) * N + n]);
    }
    lm[q][c] = mx; ls[q][c] = sum;
    __syncthreads();
    if (q == 0) {
        #pragma unroll
        for (int j = 1; j < 4; ++j) online_merge(mx, sum, lm[j][c], ls[j][c]);
        M[(long)b * N + n]  = mx;
        Sm[(long)b * N + n] = sum;
        if (C2L) C2L[(long)b * N + n] = (mx - LN2 + __logf(sum)) * LOG2E;
    }
}

// ---------------------------------------------------------------------------
// f32 -> bf16 conversion (vectorized).
__global__ LB void to_bf16(const float* __restrict__ in, ushort* __restrict__ out, long n)
{
    const long i = ((long)blockIdx.x * 256 + threadIdx.x) * 4;
    if (i >= n) return;
    const float4 v = *(const float4*)&in[i];
    ushort4 o;
    o.x = bf16rne(v.x); o.y = bf16rne(v.y); o.z = bf16rne(v.z); o.w = bf16rne(v.w);
    *(ushort4*)&out[i] = o;
}

// ---------------------------------------------------------------------------
// MFMA softmax-apply GEMM:
//   part_s[b,row,col] = sum_{k in chunk s} X[b,row,k] * exp(A[b,col,k] - Mv[b,col])
template<int MROWS>
__global__ LB void sm_gemm_mfma(const ushort* __restrict__ Xbf,
                                const float* __restrict__ A,
                                const float* __restrict__ Mv,
                                float* __restrict__ p0, float* __restrict__ p1,
                                int N)
{
    constexpr int RT = MROWS / 32;
    constexpr int TPRA = 256 / MROWS;
    __shared__ ushort ldsA[MROWS][40];
    __shared__ ushort ldsB[32][40];

    const int tid = threadIdx.x;
    const int wave = tid >> 6, lane = tid & 63;
    const int col0 = blockIdx.x * 32;
    const int s = blockIdx.y, b = blockIdx.z;
    const int K0 = s * (N / 2);

    const int scol = tid >> 3, sq = tid & 7;
    const int ar = tid / TPRA;
    const int ak = (tid % TPRA) * (32 / TPRA);
    const int wct = wave & 1;
    const int wrh = wave >> 1;
    const int fr = lane & 15, fg = lane >> 4;

    f32x4 acc[RT];
    #pragma unroll
    for (int i = 0; i < RT; ++i) acc[i] = (f32x4){0.f, 0.f, 0.f, 0.f};

    const float* ab = A + ((long)b * N + col0) * N;
    const ushort* xb = Xbf + (long)b * MROWS * N;
    const float mvl = Mv[(long)b * N + col0 + scol] * LOG2E;

    for (int k0 = K0; k0 < K0 + N / 2; k0 += 32) {
        __syncthreads();
        #pragma unroll
        for (int j = 0; j < 32 / TPRA; j += 8) {
            const short8v av = *(const short8v*)&xb[(long)ar * N + k0 + ak + j];
            *(short8v*)&ldsA[ar][ak + j] = av;
        }
        const float4 v = *(const float4*)&ab[(long)scol * N + k0 + sq * 4];
        ushort4 bfv;
        bfv.x = bf16rne(exp2f(fmaf(v.x, LOG2E, -mvl)));
        bfv.y = bf16rne(exp2f(fmaf(v.y, LOG2E, -mvl)));
        bfv.z = bf16rne(exp2f(fmaf(v.z, LOG2E, -mvl)));
        bfv.w = bf16rne(exp2f(fmaf(v.w, LOG2E, -mvl)));
        *(ushort4*)&ldsB[scol][sq * 4] = bfv;
        __syncthreads();
        const short8v bfrag = *(const short8v*)&ldsB[wct * 16 + fr][8 * fg];
        #pragma unroll
        for (int rt = 0; rt < RT; ++rt) {
            const int row = wrh * (MROWS / 2) + rt * 16 + fr;
            const short8v afrag = *(const short8v*)&ldsA[row][8 * fg];
            acc[rt] = __builtin_amdgcn_mfma_f32_16x16x32_bf16(afrag, bfrag, acc[rt], 0, 0, 0);
        }
    }

    float* pp = (s == 0) ? p0 : p1;
    #pragma unroll
    for (int rt = 0; rt < RT; ++rt) {
        #pragma unroll
        for (int r = 0; r < 4; ++r) {
            const int row = wrh * (MROWS / 2) + rt * 16 + (lane >> 4) * 4 + r;
            const int col = col0 + wct * 16 + (lane & 15);
            pp[((long)b * MROWS + row) * N + col] = acc[rt][r];
        }
    }
}

// Sum 2 K-split partials and divide by per-column softmax denom.
template<int C>
__global__ LB void sm_reduce2(const float* __restrict__ p0, const float* __restrict__ p1,
                              const float* __restrict__ denom, float* __restrict__ outp, int N)
{
    const long idx = (long)blockIdx.x * 256 + threadIdx.x;
    const int m = (int)(idx & (long)(N - 1));
    const int b = (int)(idx / ((long)C * N));
    outp[idx] = (p0[idx] + p1[idx]) / denom[(long)b * N + m];
}

// ---------------------------------------------------------------------------
// Fused: att2 = att + attT (BOTH coalesced at the same index), att3 = exp2
// fold, then 3x3 conv + BN + ReLU. Tile 64x32 (halo 66x34). grid: (8192, B).
__global__ LB void attmap_conv(const float* __restrict__ att,
                               const float* __restrict__ attT,
                               const float* __restrict__ C2L,
                               const float* __restrict__ w, const float* __restrict__ g,
                               float* __restrict__ out, int N)
{
    __shared__ float tD[34][68];
    __shared__ float ldc[66];
    const int tid = threadIdx.x;
    const int tx = tid & 63, ty = tid >> 6;
    const int x0 = (blockIdx.x & 63) * 64;
    const int y0 = (blockIdx.x >> 6) * 32;
    const int b = blockIdx.y;
    const float* ap = att + (long)b * N * N;
    const float* tp = attT + (long)b * N * N;
    const float* cp = C2L + (long)b * N;

    if (tid < 66) {
        const int xx = x0 + tid - 1;
        ldc[tid] = ((unsigned)xx < (unsigned)N) ? cp[xx] : 0.f;
    }
    __syncthreads();

    // interior columns: hx = tx+1 (xx = x0+tx, aligned coalesced)
    const float negc = -ldc[tx + 1];
    #pragma unroll
    for (int i = 0; i < 9; ++i) {
        const int hy = ty + i * 4;
        if (hy < 34) {
            const int yy = y0 + hy - 1;
            float v = 0.f;
            if ((unsigned)yy < (unsigned)N) {
                const long off = (long)yy * N + x0 + tx;
                v = exp2f(fmaf(ap[off] + tp[off], LOG2E, negc));
            }
            tD[hy][tx + 1] = v;
        }
    }
    // edge columns hx=0 (xx=x0-1) and hx=65 (xx=x0+64): 2 x 34 elements
    if (tid < 68) {
        const int c01 = tid & 1, hy = tid >> 1;
        const int hx = c01 ? 65 : 0;
        const int xx = x0 - 1 + c01 * 65;
        const int yy = y0 + hy - 1;
        float v = 0.f;
        if ((unsigned)yy < (unsigned)N && (unsigned)xx < (unsigned)N) {
            const long off = (long)yy * N + xx;
            v = exp2f(fmaf(ap[off] + tp[off], LOG2E, -ldc[hx]));
        }
        tD[hy][hx] = v;
    }
    __syncthreads();

    const float scale = g[0] * BN_SCALE, beta = g[1];
    float* ob = out + (long)b * N * N + (long)y0 * N + x0 + tx;
    #pragma unroll
    for (int rr = 0; rr < 8; ++rr) {
        const int ly = ty * 8 + rr;
        float acc = 0.f;
        #pragma unroll
        for (int ky = 0; ky < 3; ++ky)
            #pragma unroll
            for (int kx = 0; kx < 3; ++kx)
                acc = fmaf(w[ky * 3 + kx], tD[ly + ky][tx + kx], acc);
        ob[(long)ly * N] = fmaxf(fmaf(acc, scale, beta), 0.f);
    }
}

// ===========================================================================
extern "C" void kernel_launch(void* const* d_in, const int* in_sizes, int n_in,
                              void* d_out, int out_size, void* d_ws, size_t ws_size,
                              hipStream_t stream)
{
    const float* xs   = (const float*)d_in[0];
    const float* xc   = (const float*)d_in[1];
    const float* w_g1 = (const float*)d_in[2];
    const float* g_g1 = (const float*)d_in[3];
    const float* w_g2 = (const float*)d_in[4];
    const float* g_g2 = (const float*)d_in[5];
    const float* w_ls = (const float*)d_in[6];
    const float* b_ls = (const float*)d_in[7];
    const float* g_ls = (const float*)d_in[8];
    const float* w_lc = (const float*)d_in[9];
    const float* b_lc = (const float*)d_in[10];
    const float* g_lc = (const float*)d_in[11];
    const float* w_c1 = (const float*)d_in[12];
    const float* g_c1 = (const float*)d_in[13];
    const float* w_c2 = (const float*)d_in[14];
    const float* g_c2 = (const float*)d_in[15];
    const float* w_o1 = (const float*)d_in[16];
    const float* g_o1 = (const float*)d_in[17];
    const float* w_o2 = (const float*)d_in[18];
    const float* g_o2 = (const float*)d_in[19];
    const float* w_oa = (const float*)d_in[20];
    const float* g_oa = (const float*)d_in[21];

    const int B = 2, HW = 4096, N = 4096;

    // ---- workspace layout (float offsets); ws_size >= 536MB (fill counter) ----
    float* ws = (float*)d_ws;
    float* xs1    = ws;                       // 524288
    float* xc1    = ws + 524288;              // 1048576
    float* fs     = ws + 1572864;             // 262144 (conv phase)
    float* fc     = ws + 1835008;             // 262144
    float* t32    = ws + 2097152;             // 262144 (conv phase)
    // stat partials [B,32,N] = 262144 each (after att_gemm, fs/fc/t32 dead):
    float* McP    = ws + 1572864;
    float* ScP    = ws + 1835008;
    float* MrP    = ws + 2097152;
    float* SrP    = ws + 2359296;
    float* M2P    = ws + 2621440;
    float* S2P    = ws + 2883584;
    // GEMM phase (partials dead after combines):
    float* pg1    = ws + 1572864;             // K-split partial s=1 (<=1048576)
    ushort* xs1bf = (ushort*)(ws + 2621440);  // 524288 ushorts
    float* outs_w = ws + 2359296;             // 524288
    float* outc_w = ws + 2883584;             // 1048576
    float* gs_w   = ws + 3932160;             // 64
    float* gc_w   = ws + 3932224;             // 64
    float* Mc     = ws + 3932288;             // 8192
    float* Sc     = ws + 3940480;             // 8192
    float* Mr     = ws + 3948672;             // 8192
    float* Sr     = ws + 3956864;             // 8192
    float* M2     = ws + 3965056;             // 8192
    float* S2     = ws + 3973248;             // 8192
    float* C2L    = ws + 3981440;             // 8192
    float* att    = ws + 4243584;             // 33554432
    float* attT   = ws + 37798016;            // 33554432 (NEW: ws-resident)
    float* cpart  = att;                      // conv partials alias

    // ---- d_out layout ----
    float* out = (float*)d_out;
    float* out_attmap = out;                       // final att_map
    float* out_s      = out + 33554432;            // 524288
    float* out_c      = out + 34078720;            // 1048576
    float* out_gs     = out + 35127296;            // 64
    float* out_gc     = out + 35127360;            // 64
    float* pg0        = out + 33554432;            // GEMM partial s=0 (dead before out_s)
    ushort* xc1bf     = (ushort*)(out + 34603008); // dead before out_c final write

    const dim3 blk(256);
    const int ICS = 8;

    // global context s/c
    conv3x3_big<<<dim3(4, 4, B * ICS), blk, 0, stream>>>(xs, nullptr, w_g1, nullptr, cpart, 0, 64, 32, ICS);
    conv_combine<<<dim3((B * 32 * HW) / 256), blk, 0, stream>>>(cpart, g_g1, nullptr, t32, 32, ICS);
    gap_kernel<<<dim3(32, B), blk, 0, stream>>>(t32, gs_w, out_gs, 32, HW);
    conv3x3_big<<<dim3(4, 4, B * ICS), blk, 0, stream>>>(xc, nullptr, w_g2, nullptr, cpart, 0, 128, 32, ICS);
    conv_combine<<<dim3((B * 32 * HW) / 256), blk, 0, stream>>>(cpart, g_g2, nullptr, t32, 32, ICS);
    gap_kernel<<<dim3(32, B), blk, 0, stream>>>(t32, gc_w, out_gc, 32, HW);
    // local fusion convs + residual
    conv3x3_big<<<dim3(4, 8, B * ICS), blk, 0, stream>>>(xs, gs_w, w_ls, b_ls, cpart, 32, 64, 64, ICS);
    conv_combine<<<dim3((B * 64 * HW) / 256), blk, 0, stream>>>(cpart, g_ls, xs, xs1, 64, ICS);
    conv3x3_big<<<dim3(4, 16, B * ICS), blk, 0, stream>>>(xc, gc_w, w_lc, b_lc, cpart, 32, 128, 128, ICS);
    conv_combine<<<dim3((B * 128 * HW) / 256), blk, 0, stream>>>(cpart, g_lc, xc, xc1, 128, ICS);
    // attention features
    conv3x3_big<<<dim3(4, 4, B * ICS), blk, 0, stream>>>(xs1, nullptr, w_c1, nullptr, cpart, 0, 64, 32, ICS);
    conv_combine<<<dim3((B * 32 * HW) / 256), blk, 0, stream>>>(cpart, g_c1, nullptr, fs, 32, ICS);
    conv3x3_big<<<dim3(4, 4, B * ICS), blk, 0, stream>>>(xc1, nullptr, w_c2, nullptr, cpart, 0, 128, 32, ICS);
    conv_combine<<<dim3((B * 32 * HW) / 256), blk, 0, stream>>>(cpart, g_c2, nullptr, fc, 32, ICS);
    // att = fs^T fc  (+ attT, both in ws)
    att_gemm<<<dim3(16, 256, B), blk, 0, stream>>>(fs, fc, att, attT, N);
    // ONE streaming pass: all three stat partial sets
    tri_stats<<<dim3(64, 32, B), blk, 0, stream>>>(att, attT, McP, ScP, MrP, SrP, M2P, S2P, N);
    stats_comb32<<<dim3(64, B), blk, 0, stream>>>(McP, ScP, Mc, Sc, nullptr, N);
    stats_comb32<<<dim3(64, B), blk, 0, stream>>>(MrP, SrP, Mr, Sr, nullptr, N);
    stats_comb32<<<dim3(64, B), blk, 0, stream>>>(M2P, S2P, M2, S2, C2L, N);
    // bf16 conversions (stat partials dead now)
    to_bf16<<<dim3(1024), blk, 0, stream>>>(xc1, xc1bf, (long)B * 128 * N);
    to_bf16<<<dim3(512), blk, 0, stream>>>(xs1, xs1bf, (long)B * 64 * N);
    // outc = xc1 @ rowsoftmax(att)^T  via MFMA
    sm_gemm_mfma<128><<<dim3(128, 2, B), blk, 0, stream>>>(xc1bf, att, Mr, pg0, pg1, N);
    sm_reduce2<128><<<dim3((B * 128 * N) / 256), blk, 0, stream>>>(pg0, pg1, Sr, outc_w, N);
    // outs = xs1 @ colsoftmax(att)  via MFMA on attT
    sm_gemm_mfma<64><<<dim3(128, 2, B), blk, 0, stream>>>(xs1bf, attT, Mc, pg0, pg1, N);
    sm_reduce2<64><<<dim3((B * 64 * N) / 256), blk, 0, stream>>>(pg0, pg1, Sc, outs_w, N);
    // fused att2+att3+conv (att & attT both coalesced; writes final map)
    attmap_conv<<<dim3(8192, B), blk, 0, stream>>>(att, attT, C2L, w_oa, g_oa, out_attmap, N);
    // output convs + residuals (att region free again for partials)
    conv3x3_big<<<dim3(4, 8, B * ICS), blk, 0, stream>>>(outs_w, nullptr, w_o1, nullptr, cpart, 0, 64, 64, ICS);
    conv_combine<<<dim3((B * 64 * HW) / 256), blk, 0, stream>>>(cpart, g_o1, xs1, out_s, 64, ICS);
    conv3x3_big<<<dim3(4, 16, B * ICS), blk, 0, stream>>>(outc_w, nullptr, w_o2, nullptr, cpart, 0, 128, 128, ICS);
    conv_combine<<<dim3((B * 128 * HW) / 256), blk, 0, stream>>>(cpart, g_o2, xc1, out_c, 128, ICS);
}

// Round 12
// 737.235 us; speedup vs baseline: 1.5833x; 1.1275x over previous
//
#include <hip/hip_runtime.h>

// AGLI_5703716569604 — round 11: attmap 128-wide float4 tile; conv K-split
// ICS raised (32 for Cout=32 convs, 16 for the rest) for occupancy.
// B=2, ch1=64, ch2=128, H=W=64, N=4096, att [B,4096,4096].

#define LB __launch_bounds__(256)

constexpr float BN_SCALE = 0.99999500003749968f; // 1/sqrt(1+1e-5)
constexpr float NEG_BIG  = -3.402823466e38f;
constexpr float LOG2E    = 1.4426950408889634f;
constexpr float LN2      = 0.6931471805599453f;

typedef __attribute__((ext_vector_type(8))) short short8v;
typedef __attribute__((ext_vector_type(4))) float f32x4;

__device__ __forceinline__ ushort bf16rne(float f) {
    unsigned u = __float_as_uint(f);
    unsigned r = (u + 0x7FFFu + ((u >> 16) & 1u)) >> 16;
    return (ushort)r;
}

__device__ __forceinline__ void online_upd(float& mx, float& sm, float v) {
    if (v > mx) { sm = sm * __expf(mx - v) + 1.f; mx = v; }
    else        { sm += __expf(v - mx); }
}
__device__ __forceinline__ void online_merge(float& mx, float& sm, float m2, float s2) {
    const float mn = fmaxf(mx, m2);
    sm = sm * __expf(mx - mn) + s2 * __expf(m2 - mn);
    mx = mn;
}

// ---------------------------------------------------------------------------
// Stage one 34x34 halo tile (stride 35) for input channel image ib.
__device__ __forceinline__ void stage_tile(const float* __restrict__ ib,
                                           float* __restrict__ buf,
                                           int x0, int y0, int tid)
{
    #pragma unroll
    for (int r = 0; r < 5; ++r) {
        const int e = tid + r * 256;
        if (e < 1156) {
            const int hy = e / 34, hx = e % 34;
            const int yy = y0 + hy - 1, xx = x0 + hx - 1;
            float v = 0.f;
            if ((unsigned)yy < 64u && (unsigned)xx < 64u)
                v = ib[yy * 64 + xx];
            buf[hy * 35 + hx] = v;
        }
    }
}

// ---------------------------------------------------------------------------
// 3x3 conv partial over an ic-chunk (unchanged).
__global__ LB void conv3x3_big(
    const float* __restrict__ in, const float* __restrict__ gconst,
    const float* __restrict__ w, const float* __restrict__ bias,
    float* __restrict__ part, int Cg, int Cin, int Cout, int ICS)
{
    __shared__ float buf[2][34 * 35];
    __shared__ float wg[8][10];
    const int tid = threadIdx.x;
    const int tx = tid & 15, ty = tid >> 4;
    const int x0 = (blockIdx.x & 1) * 32, y0 = (blockIdx.x >> 1) * 32;
    const int oc0 = blockIdx.y * 8;
    const int b = blockIdx.z / ICS, s = blockIdx.z % ICS;
    const int chunk = Cin / ICS;
    const int ic0 = s * chunk;
    const int Ct = Cg + Cin;
    const int HW = 4096;

    float acc[8][4];
    #pragma unroll
    for (int oc = 0; oc < 8; ++oc)
        #pragma unroll
        for (int p = 0; p < 4; ++p) acc[oc][p] = 0.f;

    if (s == 0) {
        if (bias) {
            #pragma unroll
            for (int oc = 0; oc < 8; ++oc) {
                const float bv = bias[oc0 + oc];
                #pragma unroll
                for (int p = 0; p < 4; ++p) acc[oc][p] = bv;
            }
        }
        if (Cg > 0) {
            for (int e = tid; e < 72; e += 256) {
                const int oc = e / 9, k = e % 9;
                float sm = 0.f;
                for (int ic = 0; ic < Cg; ++ic)
                    sm += gconst[b * Cg + ic] * w[((long)(oc0 + oc) * Ct + ic) * 9 + k];
                wg[oc][k] = sm;
            }
            __syncthreads();
            #pragma unroll
            for (int k = 0; k < 9; ++k) {
                const int dy = k / 3 - 1, dx = k % 3 - 1;
                #pragma unroll
                for (int pr = 0; pr < 2; ++pr)
                    #pragma unroll
                    for (int pc = 0; pc < 2; ++pc) {
                        const int yy = y0 + ty * 2 + pr + dy;
                        const int xx = x0 + tx * 2 + pc + dx;
                        if ((unsigned)yy < 64u && (unsigned)xx < 64u) {
                            #pragma unroll
                            for (int oc = 0; oc < 8; ++oc)
                                acc[oc][pr * 2 + pc] += wg[oc][k];
                        }
                    }
            }
        }
    }

    const float* ib = in + ((long)b * Cin + ic0) * HW;
    stage_tile(ib, buf[0], x0, y0, tid);
    __syncthreads();
    int cur = 0;
    for (int i = 0; i < chunk; ++i) {
        if (i + 1 < chunk)
            stage_tile(ib + (long)(i + 1) * HW, buf[cur ^ 1], x0, y0, tid);
        float win[4][4];
        const float* bp = buf[cur] + (ty * 2) * 35 + tx * 2;
        #pragma unroll
        for (int r = 0; r < 4; ++r) {
            const float2 a = *(const float2*)&bp[r * 35];
            const float2 c = *(const float2*)&bp[r * 35 + 2];
            win[r][0] = a.x; win[r][1] = a.y; win[r][2] = c.x; win[r][3] = c.y;
        }
        const float* wq = w + ((long)oc0 * Ct + Cg + ic0 + i) * 9;
        #pragma unroll
        for (int oc = 0; oc < 8; ++oc) {
            const float* wo = wq + (long)oc * Ct * 9;
            #pragma unroll
            for (int dy = 0; dy < 3; ++dy)
                #pragma unroll
                for (int dx = 0; dx < 3; ++dx) {
                    const float wv = wo[dy * 3 + dx];
                    #pragma unroll
                    for (int pr = 0; pr < 2; ++pr)
                        #pragma unroll
                        for (int pc = 0; pc < 2; ++pc)
                            acc[oc][pr * 2 + pc] =
                                fmaf(wv, win[pr + dy][pc + dx], acc[oc][pr * 2 + pc]);
                }
        }
        __syncthreads();
        cur ^= 1;
    }

    #pragma unroll
    for (int oc = 0; oc < 8; ++oc) {
        #pragma unroll
        for (int pr = 0; pr < 2; ++pr) {
            float* q = part + (((long)s * 2 + b) * Cout + oc0 + oc) * (long)HW
                       + (y0 + ty * 2 + pr) * 64 + x0 + tx * 2;
            *(float2*)q = make_float2(acc[oc][pr * 2], acc[oc][pr * 2 + 1]);
        }
    }
}

// ---------------------------------------------------------------------------
__global__ LB void conv_combine(const float* __restrict__ part,
                                const float* __restrict__ bn,
                                const float* __restrict__ residual,
                                float* __restrict__ out,
                                int Cout, int ICS)
{
    const long idx = (long)blockIdx.x * 256 + threadIdx.x;
    const int hw = (int)(idx & 4095);
    const long t = idx >> 12;
    const int c = (int)(t % Cout);
    const int b = (int)(t / Cout);
    float v = 0.f;
    for (int s = 0; s < ICS; ++s)
        v += part[(((long)s * 2 + b) * Cout + c) * 4096 + hw];
    const float scale = bn[c] * BN_SCALE, beta = bn[Cout + c];
    float r = fmaxf(fmaf(v, scale, beta), 0.f);
    if (residual) r += residual[idx];
    out[idx] = r;
}

// ---------------------------------------------------------------------------
__global__ LB void gap_kernel(const float* __restrict__ in,
                              float* __restrict__ o1, float* __restrict__ o2,
                              int C, int HW)
{
    const int c = blockIdx.x, b = blockIdx.y;
    const float* p = in + ((long)b * C + c) * HW;
    float s = 0.f;
    for (int i = threadIdx.x; i < HW; i += 256) s += p[i];
    #pragma unroll
    for (int off = 32; off; off >>= 1) s += __shfl_down(s, off);
    __shared__ float red[4];
    if ((threadIdx.x & 63) == 0) red[threadIdx.x >> 6] = s;
    __syncthreads();
    if (threadIdx.x == 0) {
        const float t = (red[0] + red[1] + red[2] + red[3]) / (float)HW;
        o1[b * C + c] = t;
        o2[b * C + c] = t;
    }
}

// ---------------------------------------------------------------------------
// att[b,n,m] = sum_c fs[b,c,n] * fc[b,c,m], C=32. Also writes attT[b,m,n].
__global__ LB void att_gemm(const float* __restrict__ fs, const float* __restrict__ fc,
                            float* __restrict__ att, float* __restrict__ attT, int N)
{
    __shared__ float lfs[32][17];
    const int tid = threadIdx.x;
    const int m  = blockIdx.x * 256 + tid;
    const int n0 = blockIdx.y * 16;
    const int b  = blockIdx.z;
    for (int i = tid; i < 32 * 16; i += 256) {
        const int c = i >> 4, nn = i & 15;
        lfs[c][nn] = fs[((long)b * 32 + c) * N + n0 + nn];
    }
    __syncthreads();
    float acc[16];
    #pragma unroll
    for (int i = 0; i < 16; ++i) acc[i] = 0.f;
    const float* fcp = fc + (long)b * 32 * N + m;
    #pragma unroll
    for (int c = 0; c < 32; ++c) {
        const float f = fcp[(long)c * N];
        #pragma unroll
        for (int nn = 0; nn < 16; ++nn) acc[nn] = fmaf(lfs[c][nn], f, acc[nn]);
    }
    float* op = att + ((long)b * N + n0) * N + m;
    #pragma unroll
    for (int nn = 0; nn < 16; ++nn) op[(long)nn * N] = acc[nn];
    float* opT = attT + ((long)b * N + m) * N + n0;
    #pragma unroll
    for (int q = 0; q < 4; ++q)
        *(float4*)&opT[q * 4] = make_float4(acc[q*4], acc[q*4+1], acc[q*4+2], acc[q*4+3]);
}

// ---------------------------------------------------------------------------
// ONE streaming pass over att+attT producing all 3 stat partial sets [B,32,N].
__global__ LB void tri_stats(const float* __restrict__ att, const float* __restrict__ attT,
                             float* __restrict__ McP, float* __restrict__ ScP,
                             float* __restrict__ MrP, float* __restrict__ SrP,
                             float* __restrict__ M2P, float* __restrict__ S2P, int N)
{
    __shared__ float lm[3][4][64], ls[3][4][64];
    const int c = threadIdx.x & 63, q = threadIdx.x >> 6;
    const int m = blockIdx.x * 64 + c;
    const int y = blockIdx.y, b = blockIdx.z;
    const long base = (long)b * N * N + ((long)y * 128 + q) * N + m;
    float mc = NEG_BIG, sc = 0.f, mr = NEG_BIG, sr = 0.f, m2 = NEG_BIG, s2 = 0.f;
    for (int r = 0; r < 32; ++r) {
        const long off = base + (long)r * 4 * N;
        const float a = att[off];
        const float t = attT[off];
        online_upd(mc, sc, a);
        online_upd(mr, sr, t);
        online_upd(m2, s2, a + t);
    }
    lm[0][q][c] = mc; ls[0][q][c] = sc;
    lm[1][q][c] = mr; ls[1][q][c] = sr;
    lm[2][q][c] = m2; ls[2][q][c] = s2;
    __syncthreads();
    if (q < 3) {
        float M = lm[q][0][c], S = ls[q][0][c];
        #pragma unroll
        for (int j = 1; j < 4; ++j) online_merge(M, S, lm[q][j][c], ls[q][j][c]);
        float* Pm = (q == 0) ? McP : ((q == 1) ? MrP : M2P);
        float* Ps = (q == 0) ? ScP : ((q == 1) ? SrP : S2P);
        Pm[((long)(b * 32 + y)) * N + m] = M;
        Ps[((long)(b * 32 + y)) * N + m] = S;
    }
}

// ---------------------------------------------------------------------------
// Combine 32 partial (max,sumexp) sets -> final stats (+ optional C2L).
__global__ LB void stats_comb32(const float* __restrict__ Mp, const float* __restrict__ Sp,
                                float* __restrict__ M, float* __restrict__ Sm,
                                float* __restrict__ C2L, int N)
{
    __shared__ float lm[4][64], ls[4][64];
    const int c = threadIdx.x & 63, q = threadIdx.x >> 6;
    const int n = blockIdx.x * 64 + c;
    const int b = blockIdx.y;
    float mx = NEG_BIG, sum = 0.f;
    #pragma unroll
    for (int j = 0; j < 8; ++j) {
        const int s = q * 8 + j;
        online_merge(mx, sum, Mp[((long)(b * 32 + s)) * N + n], Sp[((long)(b * 32 + s)) * N + n]);
    }
    lm[q][c] = mx; ls[q][c] = sum;
    __syncthreads();
    if (q == 0) {
        #pragma unroll
        for (int j = 1; j < 4; ++j) online_merge(mx, sum, lm[j][c], ls[j][c]);
        M[(long)b * N + n]  = mx;
        Sm[(long)b * N + n] = sum;
        if (C2L) C2L[(long)b * N + n] = (mx - LN2 + __logf(sum)) * LOG2E;
    }
}

// ---------------------------------------------------------------------------
// f32 -> bf16 conversion (vectorized).
__global__ LB void to_bf16(const float* __restrict__ in, ushort* __restrict__ out, long n)
{
    const long i = ((long)blockIdx.x * 256 + threadIdx.x) * 4;
    if (i >= n) return;
    const float4 v = *(const float4*)&in[i];
    ushort4 o;
    o.x = bf16rne(v.x); o.y = bf16rne(v.y); o.z = bf16rne(v.z); o.w = bf16rne(v.w);
    *(ushort4*)&out[i] = o;
}

// ---------------------------------------------------------------------------
// MFMA softmax-apply GEMM:
//   part_s[b,row,col] = sum_{k in chunk s} X[b,row,k] * exp(A[b,col,k] - Mv[b,col])
template<int MROWS>
__global__ LB void sm_gemm_mfma(const ushort* __restrict__ Xbf,
                                const float* __restrict__ A,
                                const float* __restrict__ Mv,
                                float* __restrict__ p0, float* __restrict__ p1,
                                int N)
{
    constexpr int RT = MROWS / 32;
    constexpr int TPRA = 256 / MROWS;
    __shared__ ushort ldsA[MROWS][40];
    __shared__ ushort ldsB[32][40];

    const int tid = threadIdx.x;
    const int wave = tid >> 6, lane = tid & 63;
    const int col0 = blockIdx.x * 32;
    const int s = blockIdx.y, b = blockIdx.z;
    const int K0 = s * (N / 2);

    const int scol = tid >> 3, sq = tid & 7;
    const int ar = tid / TPRA;
    const int ak = (tid % TPRA) * (32 / TPRA);
    const int wct = wave & 1;
    const int wrh = wave >> 1;
    const int fr = lane & 15, fg = lane >> 4;

    f32x4 acc[RT];
    #pragma unroll
    for (int i = 0; i < RT; ++i) acc[i] = (f32x4){0.f, 0.f, 0.f, 0.f};

    const float* ab = A + ((long)b * N + col0) * N;
    const ushort* xb = Xbf + (long)b * MROWS * N;
    const float mvl = Mv[(long)b * N + col0 + scol] * LOG2E;

    for (int k0 = K0; k0 < K0 + N / 2; k0 += 32) {
        __syncthreads();
        #pragma unroll
        for (int j = 0; j < 32 / TPRA; j += 8) {
            const short8v av = *(const short8v*)&xb[(long)ar * N + k0 + ak + j];
            *(short8v*)&ldsA[ar][ak + j] = av;
        }
        const float4 v = *(const float4*)&ab[(long)scol * N + k0 + sq * 4];
        ushort4 bfv;
        bfv.x = bf16rne(exp2f(fmaf(v.x, LOG2E, -mvl)));
        bfv.y = bf16rne(exp2f(fmaf(v.y, LOG2E, -mvl)));
        bfv.z = bf16rne(exp2f(fmaf(v.z, LOG2E, -mvl)));
        bfv.w = bf16rne(exp2f(fmaf(v.w, LOG2E, -mvl)));
        *(ushort4*)&ldsB[scol][sq * 4] = bfv;
        __syncthreads();
        const short8v bfrag = *(const short8v*)&ldsB[wct * 16 + fr][8 * fg];
        #pragma unroll
        for (int rt = 0; rt < RT; ++rt) {
            const int row = wrh * (MROWS / 2) + rt * 16 + fr;
            const short8v afrag = *(const short8v*)&ldsA[row][8 * fg];
            acc[rt] = __builtin_amdgcn_mfma_f32_16x16x32_bf16(afrag, bfrag, acc[rt], 0, 0, 0);
        }
    }

    float* pp = (s == 0) ? p0 : p1;
    #pragma unroll
    for (int rt = 0; rt < RT; ++rt) {
        #pragma unroll
        for (int r = 0; r < 4; ++r) {
            const int row = wrh * (MROWS / 2) + rt * 16 + (lane >> 4) * 4 + r;
            const int col = col0 + wct * 16 + (lane & 15);
            pp[((long)b * MROWS + row) * N + col] = acc[rt][r];
        }
    }
}

// Sum 2 K-split partials and divide by per-column softmax denom.
template<int C>
__global__ LB void sm_reduce2(const float* __restrict__ p0, const float* __restrict__ p1,
                              const float* __restrict__ denom, float* __restrict__ outp, int N)
{
    const long idx = (long)blockIdx.x * 256 + threadIdx.x;
    const int m = (int)(idx & (long)(N - 1));
    const int b = (int)(idx / ((long)C * N));
    outp[idx] = (p0[idx] + p1[idx]) / denom[(long)b * N + m];
}

// ---------------------------------------------------------------------------
// Fused: att2 = att + attT (both coalesced float4), att3 = exp2 fold, then
// 3x3 conv + BN + ReLU. Tile 128x32 (halo 130x34). grid: (4096, B).
__global__ LB void attmap_conv(const float* __restrict__ att,
                               const float* __restrict__ attT,
                               const float* __restrict__ C2L,
                               const float* __restrict__ w, const float* __restrict__ g,
                               float* __restrict__ out, int N)
{
    __shared__ float tD[34][132];   // cols: 0 = left halo, 1..128 interior, 129 = right halo
    __shared__ float ldc[130];
    const int tid = threadIdx.x;
    const int x0 = (blockIdx.x & 31) * 128;
    const int y0 = (blockIdx.x >> 5) * 32;
    const int b = blockIdx.y;
    const float* ap = att + (long)b * N * N;
    const float* tp = attT + (long)b * N * N;
    const float* cp = C2L + (long)b * N;

    if (tid < 130) {
        const int xx = x0 + tid - 1;
        ldc[tid] = ((unsigned)xx < (unsigned)N) ? cp[xx] : 0.f;
    }
    __syncthreads();

    // interior: float4 on both streams. 32 col-groups x 8 rows per pass.
    {
        const int xg = (tid & 31) * 4;      // 0..124
        const int rg = tid >> 5;            // 0..7
        #pragma unroll
        for (int i = 0; i < 5; ++i) {
            const int hy = rg + i * 8;
            if (hy < 34) {
                const int yy = y0 + hy - 1;
                float4 v = make_float4(0.f, 0.f, 0.f, 0.f);
                if ((unsigned)yy < (unsigned)N) {
                    const long off = (long)yy * N + x0 + xg;
                    const float4 a = *(const float4*)&ap[off];
                    const float4 t = *(const float4*)&tp[off];
                    v.x = exp2f(fmaf(a.x + t.x, LOG2E, -ldc[xg + 1]));
                    v.y = exp2f(fmaf(a.y + t.y, LOG2E, -ldc[xg + 2]));
                    v.z = exp2f(fmaf(a.z + t.z, LOG2E, -ldc[xg + 3]));
                    v.w = exp2f(fmaf(a.w + t.w, LOG2E, -ldc[xg + 4]));
                }
                tD[hy][xg + 1] = v.x;
                tD[hy][xg + 2] = v.y;
                tD[hy][xg + 3] = v.z;
                tD[hy][xg + 4] = v.w;
            }
        }
    }
    // edge columns: hx=0 (xx=x0-1) and hx=129 (xx=x0+128): 2 x 34 elements
    if (tid < 68) {
        const int c01 = tid & 1, hy = tid >> 1;
        const int hx = c01 ? 129 : 0;
        const int xx = c01 ? (x0 + 128) : (x0 - 1);
        const int yy = y0 + hy - 1;
        float v = 0.f;
        if ((unsigned)yy < (unsigned)N && (unsigned)xx < (unsigned)N) {
            const long off = (long)yy * N + xx;
            v = exp2f(fmaf(ap[off] + tp[off], LOG2E, -ldc[hx]));
        }
        tD[hy][hx] = v;
    }
    __syncthreads();

    const float scale = g[0] * BN_SCALE, beta = g[1];
    const int tx2 = tid & 127, tyg = tid >> 7;   // 128 cols, 2 row-groups
    float* ob = out + (long)b * N * N + (long)y0 * N + x0 + tx2;
    #pragma unroll
    for (int rr = 0; rr < 16; ++rr) {
        const int ly = tyg + rr * 2;
        float acc = 0.f;
        #pragma unroll
        for (int ky = 0; ky < 3; ++ky)
            #pragma unroll
            for (int kx = 0; kx < 3; ++kx)
                acc = fmaf(w[ky * 3 + kx], tD[ly + ky][tx2 + kx], acc);
        ob[(long)ly * N] = fmaxf(fmaf(acc, scale, beta), 0.f);
    }
}

// ===========================================================================
extern "C" void kernel_launch(void* const* d_in, const int* in_sizes, int n_in,
                              void* d_out, int out_size, void* d_ws, size_t ws_size,
                              hipStream_t stream)
{
    const float* xs   = (const float*)d_in[0];
    const float* xc   = (const float*)d_in[1];
    const float* w_g1 = (const float*)d_in[2];
    const float* g_g1 = (const float*)d_in[3];
    const float* w_g2 = (const float*)d_in[4];
    const float* g_g2 = (const float*)d_in[5];
    const float* w_ls = (const float*)d_in[6];
    const float* b_ls = (const float*)d_in[7];
    const float* g_ls = (const float*)d_in[8];
    const float* w_lc = (const float*)d_in[9];
    const float* b_lc = (const float*)d_in[10];
    const float* g_lc = (const float*)d_in[11];
    const float* w_c1 = (const float*)d_in[12];
    const float* g_c1 = (const float*)d_in[13];
    const float* w_c2 = (const float*)d_in[14];
    const float* g_c2 = (const float*)d_in[15];
    const float* w_o1 = (const float*)d_in[16];
    const float* g_o1 = (const float*)d_in[17];
    const float* w_o2 = (const float*)d_in[18];
    const float* g_o2 = (const float*)d_in[19];
    const float* w_oa = (const float*)d_in[20];
    const float* g_oa = (const float*)d_in[21];

    const int B = 2, HW = 4096, N = 4096;

    // ---- workspace layout (float offsets); ws_size >= 536MB ----
    float* ws = (float*)d_ws;
    float* xs1    = ws;                       // 524288
    float* xc1    = ws + 524288;              // 1048576
    float* fs     = ws + 1572864;             // 262144 (conv phase)
    float* fc     = ws + 1835008;             // 262144
    float* t32    = ws + 2097152;             // 262144 (conv phase)
    // stat partials [B,32,N] = 262144 each (after att_gemm, fs/fc/t32 dead):
    float* McP    = ws + 1572864;
    float* ScP    = ws + 1835008;
    float* MrP    = ws + 2097152;
    float* SrP    = ws + 2359296;
    float* M2P    = ws + 2621440;
    float* S2P    = ws + 2883584;
    // GEMM phase (partials dead after combines):
    float* pg1    = ws + 1572864;             // K-split partial s=1 (<=1048576)
    ushort* xs1bf = (ushort*)(ws + 2621440);  // 524288 ushorts
    float* outs_w = ws + 2359296;             // 524288
    float* outc_w = ws + 2883584;             // 1048576
    float* gs_w   = ws + 3932160;             // 64
    float* gc_w   = ws + 3932224;             // 64
    float* Mc     = ws + 3932288;             // 8192
    float* Sc     = ws + 3940480;             // 8192
    float* Mr     = ws + 3948672;             // 8192
    float* Sr     = ws + 3956864;             // 8192
    float* M2     = ws + 3965056;             // 8192
    float* S2     = ws + 3973248;             // 8192
    float* C2L    = ws + 3981440;             // 8192
    float* att    = ws + 4243584;             // 33554432
    float* attT   = ws + 37798016;            // 33554432
    float* cpart  = att;                      // conv partials alias (max 67MB)

    // ---- d_out layout ----
    float* out = (float*)d_out;
    float* out_attmap = out;                       // final att_map
    float* out_s      = out + 33554432;            // 524288
    float* out_c      = out + 34078720;            // 1048576
    float* out_gs     = out + 35127296;            // 64
    float* out_gc     = out + 35127360;            // 64
    float* pg0        = out + 33554432;            // GEMM partial s=0 (dead before out_s)
    ushort* xc1bf     = (ushort*)(out + 34603008); // dead before out_c final write

    const dim3 blk(256);

    // global context s/c (Cout=32 convs: ICS=32 for occupancy)
    conv3x3_big<<<dim3(4, 4, B * 32), blk, 0, stream>>>(xs, nullptr, w_g1, nullptr, cpart, 0, 64, 32, 32);
    conv_combine<<<dim3((B * 32 * HW) / 256), blk, 0, stream>>>(cpart, g_g1, nullptr, t32, 32, 32);
    gap_kernel<<<dim3(32, B), blk, 0, stream>>>(t32, gs_w, out_gs, 32, HW);
    conv3x3_big<<<dim3(4, 4, B * 32), blk, 0, stream>>>(xc, nullptr, w_g2, nullptr, cpart, 0, 128, 32, 32);
    conv_combine<<<dim3((B * 32 * HW) / 256), blk, 0, stream>>>(cpart, g_g2, nullptr, t32, 32, 32);
    gap_kernel<<<dim3(32, B), blk, 0, stream>>>(t32, gc_w, out_gc, 32, HW);
    // local fusion convs + residual (ICS=16)
    conv3x3_big<<<dim3(4, 8, B * 16), blk, 0, stream>>>(xs, gs_w, w_ls, b_ls, cpart, 32, 64, 64, 16);
    conv_combine<<<dim3((B * 64 * HW) / 256), blk, 0, stream>>>(cpart, g_ls, xs, xs1, 64, 16);
    conv3x3_big<<<dim3(4, 16, B * 16), blk, 0, stream>>>(xc, gc_w, w_lc, b_lc, cpart, 32, 128, 128, 16);
    conv_combine<<<dim3((B * 128 * HW) / 256), blk, 0, stream>>>(cpart, g_lc, xc, xc1, 128, 16);
    // attention features (ICS=32)
    conv3x3_big<<<dim3(4, 4, B * 32), blk, 0, stream>>>(xs1, nullptr, w_c1, nullptr, cpart, 0, 64, 32, 32);
    conv_combine<<<dim3((B * 32 * HW) / 256), blk, 0, stream>>>(cpart, g_c1, nullptr, fs, 32, 32);
    conv3x3_big<<<dim3(4, 4, B * 32), blk, 0, stream>>>(xc1, nullptr, w_c2, nullptr, cpart, 0, 128, 32, 32);
    conv_combine<<<dim3((B * 32 * HW) / 256), blk, 0, stream>>>(cpart, g_c2, nullptr, fc, 32, 32);
    // att = fs^T fc  (+ attT, both in ws)
    att_gemm<<<dim3(16, 256, B), blk, 0, stream>>>(fs, fc, att, attT, N);
    // ONE streaming pass: all three stat partial sets
    tri_stats<<<dim3(64, 32, B), blk, 0, stream>>>(att, attT, McP, ScP, MrP, SrP, M2P, S2P, N);
    stats_comb32<<<dim3(64, B), blk, 0, stream>>>(McP, ScP, Mc, Sc, nullptr, N);
    stats_comb32<<<dim3(64, B), blk, 0, stream>>>(MrP, SrP, Mr, Sr, nullptr, N);
    stats_comb32<<<dim3(64, B), blk, 0, stream>>>(M2P, S2P, M2, S2, C2L, N);
    // bf16 conversions (stat partials dead now)
    to_bf16<<<dim3(1024), blk, 0, stream>>>(xc1, xc1bf, (long)B * 128 * N);
    to_bf16<<<dim3(512), blk, 0, stream>>>(xs1, xs1bf, (long)B * 64 * N);
    // outc = xc1 @ rowsoftmax(att)^T  via MFMA
    sm_gemm_mfma<128><<<dim3(128, 2, B), blk, 0, stream>>>(xc1bf, att, Mr, pg0, pg1, N);
    sm_reduce2<128><<<dim3((B * 128 * N) / 256), blk, 0, stream>>>(pg0, pg1, Sr, outc_w, N);
    // outs = xs1 @ colsoftmax(att)  via MFMA on attT
    sm_gemm_mfma<64><<<dim3(128, 2, B), blk, 0, stream>>>(xs1bf, attT, Mc, pg0, pg1, N);
    sm_reduce2<64><<<dim3((B * 64 * N) / 256), blk, 0, stream>>>(pg0, pg1, Sc, outs_w, N);
    // fused att2+att3+conv (float4 dual-stream; writes final map)
    attmap_conv<<<dim3(4096, B), blk, 0, stream>>>(att, attT, C2L, w_oa, g_oa, out_attmap, N);
    // output convs + residuals (att region free again for partials)
    conv3x3_big<<<dim3(4, 8, B * 16), blk, 0, stream>>>(outs_w, nullptr, w_o1, nullptr, cpart, 0, 64, 64, 16);
    conv_combine<<<dim3((B * 64 * HW) / 256), blk, 0, stream>>>(cpart, g_o1, xs1, out_s, 64, 16);
    conv3x3_big<<<dim3(4, 16, B * 16), blk, 0, stream>>>(outc_w, nullptr, w_o2, nullptr, cpart, 0, 128, 128, 16);
    conv_combine<<<dim3((B * 128 * HW) / 256), blk, 0, stream>>>(cpart, g_o2, xc1, out_c, 128, 16);
}